// Round 5
// baseline (641.409 us; speedup 1.0000x reference)
//
#include <hip/hip_runtime.h>

// H2GCN forward, bf16 activations in fused Jh[N,960]:
//   cols [0,64)=h [64,192)=c0 [192,448)=c1 [448,960)=c2.
// CSR build = two-level LDS counting sort (r10).
// r12: v_pk_fma_f32 + 16B gathers + 8-edge batches (543.7us verified).
// r13/r14 (XCD-pinned CONCURRENT feature slices): FAILED — FETCH 230->417MB.
//   blockIdx%8->XCD pinning doesn't hold; concurrent slices multiply the
//   instantaneous footprint. Lesson: placement-independent mechanisms only.
// r15: column-grouped edges (bucket_sort key = localrow*7 + col>>13): +10us
//   (533.9us, FETCH 230->212MB). Soft phasing only; kept (helps warmup).
// r16: SERIALIZED per-slice launches. Slicing over source features:
//   conv0: 2 x 32 bf16 feats, conv1: 4 x 32 bf16, conv2: 4 x 64 fp8 —
//   every slice = ONE 64B line per row = 3.2MB, fits EVERY XCD's 4MiB L2.
//   Same-stream launches serialize fully -> whole GPU gathers from one
//   3.2MB slice at a time; after ~26MB compulsory warm the gather runs at
//   L2 BW (34.5TB/s) not the 2.8TB/s miss path. No placement assumption.
//   LPR=4: 4 lanes x 16B = exactly the row's slice line per edge.
//   Per-output-feature accumulation order unchanged vs r15.
// fp8 ONLY at the leaf conv (r11: fp8 earlier cascades, absmax FAIL).
// Embed + Head: MFMA 16x16x32 bf16, weights pre-packed to B-fragment layout.

#define NN  50000
#define E1N 800000
#define E2N 1600000
#define LD  960
#define NT  3125         // 16-node tiles
#define NBKT 391         // 128-row buckets
#define CHUNK 8192
#define G1B 98           // ceil(E1N/CHUNK)
#define G2B 196          // ceil(E2N/CHUNK)
#define NCG 7            // column groups of 8192 nodes
#define GBS 782          // ceil(NN/64): row-groups of 64 rows (slice kernels)

typedef short bf16x8 __attribute__((ext_vector_type(8)));
typedef float f32x4  __attribute__((ext_vector_type(4)));
typedef float f32x2  __attribute__((ext_vector_type(2)));

__device__ __forceinline__ float bfl(unsigned int w) { return __uint_as_float(w << 16); }
__device__ __forceinline__ float bfh(unsigned int w) { return __uint_as_float(w & 0xFFFF0000u); }
__device__ __forceinline__ float bf2f(unsigned short u) { return __uint_as_float(((unsigned int)u) << 16); }
__device__ __forceinline__ unsigned short f2bf(float f) {         // RNE
    unsigned int u = __float_as_uint(f);
    u += 0x7FFFu + ((u >> 16) & 1u);
    return (unsigned short)(u >> 16);
}
__device__ __forceinline__ unsigned int pack2(float a, float b) {
    return (unsigned int)f2bf(a) | ((unsigned int)f2bf(b) << 16);
}
__device__ __forceinline__ unsigned int packfp8(float a, float b, float c, float d) {
    int w = __builtin_amdgcn_cvt_pk_fp8_f32(a, b, 0, false);
    w     = __builtin_amdgcn_cvt_pk_fp8_f32(c, d, w, true);
    return (unsigned int)w;
}
// packed f32 fma (v_pk_fma_f32 on gfx950); identical per-lane rounding to fmaf
__device__ __forceinline__ f32x2 pkfma(f32x2 a, f32x2 b, f32x2 c) {
#if __has_builtin(__builtin_elementwise_fma)
    return __builtin_elementwise_fma(a, b, c);
#else
    return (f32x2){fmaf(a[0], b[0], c[0]), fmaf(a[1], b[1], c[1])};
#endif
}
// bf16 pair (packed in a u32) -> f32x2 {lo, hi}
__device__ __forceinline__ f32x2 bf2(unsigned int w) {
    return (f32x2){bfl(w), bfh(w)};
}

// ---------------- CSR build ----------------

__global__ __launch_bounds__(256) void zero_kernel(float* c, int nc) {
    int i = blockIdx.x * 256 + threadIdx.x;
    if (i < nc) c[i] = 0.f;
}

__global__ __launch_bounds__(256) void bucket_count_kernel(const int* __restrict__ r1,
                                                           const int* __restrict__ r2,
                                                           int* __restrict__ bc1, int* __restrict__ bc2) {
    __shared__ int cnt[NBKT];
    for (int t = threadIdx.x; t < NBKT; t += 256) cnt[t] = 0;
    __syncthreads();
    int blk = blockIdx.x;
    const int* r; int base, lim; int* bc;
    if (blk < G1B) { r = r1; base = blk * CHUNK; lim = min(base + CHUNK, E1N); bc = bc1 + blk * NBKT; }
    else { int b2 = blk - G1B; r = r2; base = b2 * CHUNK; lim = min(base + CHUNK, E2N); bc = bc2 + b2 * NBKT; }
    for (int i = base + threadIdx.x; i < lim; i += 256)
        atomicAdd(&cnt[r[i] >> 7], 1);
    __syncthreads();
    for (int t = threadIdx.x; t < NBKT; t += 256) bc[t] = cnt[t];
}

__global__ __launch_bounds__(512) void bucket_scan_kernel(int* __restrict__ bc1, int* __restrict__ bc2) {
    __shared__ int s[512];
    int t = threadIdx.x;
    int tot1 = 0, tot2 = 0;
    if (t < NBKT) {
        for (int b = 0; b < G1B; b++) tot1 += bc1[b * NBKT + t];
        for (int b = 0; b < G2B; b++) tot2 += bc2[b * NBKT + t];
    }
    s[t] = (t < NBKT) ? tot1 : 0;
    __syncthreads();
    for (int off = 1; off < 512; off <<= 1) {
        int v = (t >= off) ? s[t - off] : 0;
        __syncthreads(); s[t] += v; __syncthreads();
    }
    int base1 = ((t < NBKT) ? s[t] : 0) - tot1;
    __syncthreads();
    s[t] = (t < NBKT) ? tot2 : 0;
    __syncthreads();
    for (int off = 1; off < 512; off <<= 1) {
        int v = (t >= off) ? s[t - off] : 0;
        __syncthreads(); s[t] += v; __syncthreads();
    }
    int base2 = ((t < NBKT) ? s[t] : 0) - tot2;
    if (t < NBKT) {
        int run = base1;
        for (int b = 0; b < G1B; b++) { int v = bc1[b * NBKT + t]; bc1[b * NBKT + t] = run; run += v; }
        run = base2;
        for (int b = 0; b < G2B; b++) { int v = bc2[b * NBKT + t]; bc2[b * NBKT + t] = run; run += v; }
    }
}

__global__ __launch_bounds__(256) void bucket_place_kernel(
        const int* __restrict__ r1, const int* __restrict__ c1, const float* __restrict__ v1,
        const int* __restrict__ r2, const int* __restrict__ c2, const float* __restrict__ v2,
        const int* __restrict__ bc1, const int* __restrict__ bc2,
        uint2* __restrict__ T1, uint2* __restrict__ T2) {
    __shared__ int pos[NBKT];
    int blk = blockIdx.x;
    const int *r, *c; const float* v; int base, lim; const int* bc; uint2* T;
    if (blk < G1B) { r = r1; c = c1; v = v1; base = blk * CHUNK; lim = min(base + CHUNK, E1N);
                     bc = bc1 + blk * NBKT; T = T1; }
    else { int b2 = blk - G1B; r = r2; c = c2; v = v2; base = b2 * CHUNK; lim = min(base + CHUNK, E2N);
           bc = bc2 + b2 * NBKT; T = T2; }
    for (int t = threadIdx.x; t < NBKT; t += 256) pos[t] = bc[t];
    __syncthreads();
    for (int i = base + threadIdx.x; i < lim; i += 256) {
        int row = r[i];
        int p = atomicAdd(&pos[row >> 7], 1);
        T[p] = make_uint2(((unsigned)c[i] << 16) | (unsigned)row, __float_as_uint(v[i]));
    }
}

// Second-level sort: key = localrow*NCG + colgroup (col>>13). Produces CSR
// where each row's edges are grouped by ascending 8192-node column group.
__global__ __launch_bounds__(256) void bucket_sort_kernel(
        const int* __restrict__ bb1, const uint2* __restrict__ T1, int* __restrict__ rp1, unsigned int* __restrict__ Ed1,
        const int* __restrict__ bb2, const uint2* __restrict__ T2, int* __restrict__ rp2, unsigned int* __restrict__ Ed2) {
    int b = blockIdx.x % NBKT;
    int g = blockIdx.x / NBKT;
    const int* bb = g ? bb2 : bb1;
    const uint2* T = g ? T2 : T1;
    int* rp = g ? rp2 : rp1;
    unsigned int* Ed = g ? Ed2 : Ed1;
    int EN = g ? E2N : E1N;
    int beg = bb[b];
    int end = (b == NBKT - 1) ? EN : bb[b + 1];
    int R0 = b * 128;
    int nrows = min(128, NN - R0);
    // keys: 0 .. 128*NCG-1 = 895. counts stored at cnt[key+1]; cnt[0]=0.
    __shared__ int cnt[1024];
    __shared__ int cur[896];
    __shared__ int ps[256];
    int t = threadIdx.x;
    for (int i = t; i < 1024; i += 256) cnt[i] = 0;
    __syncthreads();
    for (int i = beg + t; i < end; i += 256) {
        unsigned int x = T[i].x;
        int lr = (x & 0xFFFFu) & 127;
        int cg = (int)(x >> 29);            // (col>>13): col in bits [16,32) -> >>29
        atomicAdd(&cnt[lr * NCG + cg + 1], 1);
    }
    __syncthreads();
    // inclusive scan of cnt[0..1023], 4 elems/thread
    int b0 = t * 4;
    int c0 = cnt[b0], c1 = cnt[b0 + 1], c2 = cnt[b0 + 2], c3 = cnt[b0 + 3];
    int s1 = c0 + c1, s2 = s1 + c2, s3 = s2 + c3;
    ps[t] = s3;
    __syncthreads();
    for (int off = 1; off < 256; off <<= 1) {
        int v = (t >= off) ? ps[t - off] : 0;
        __syncthreads(); ps[t] += v; __syncthreads();
    }
    int base = (t > 0) ? ps[t - 1] : 0;
    cnt[b0] = base + c0; cnt[b0 + 1] = base + s1;
    cnt[b0 + 2] = base + s2; cnt[b0 + 3] = base + s3;
    __syncthreads();
    // cnt[k] (inclusive scan at index k) == exclusive prefix for key k
    for (int k = t; k < 896; k += 256) cur[k] = beg + cnt[k];
    if (t < nrows) rp[R0 + t] = beg + cnt[t * NCG];
    if (b == NBKT - 1 && t == 0) rp[NN] = end;
    __syncthreads();
    for (int i = beg + t; i < end; i += 256) {
        uint2 rec = T[i];
        int lr = (rec.x & 0xFFFFu) & 127;
        int cg = (int)(rec.x >> 29);
        int p = atomicAdd(&cur[lr * NCG + cg], 1);
        Ed[p] = (rec.x & 0xFFFF0000u) | (unsigned)f2bf(__uint_as_float(rec.y));
    }
}

// ---------------- weight -> bf16 B-fragment pack ----------------
__global__ __launch_bounds__(256) void packw_kernel(const float* __restrict__ W, unsigned short* __restrict__ Wb,
                                                    int NC, int kbs, int total) {
    int i = blockIdx.x * 256 + threadIdx.x;
    if (i >= total) return;
    int lane  = i & 63;
    int kb    = (i >> 6) % kbs;
    int ctile = i / (kbs * 64);
    int n  = ctile * 16 + (lane & 15);
    int k0 = kb * 32 + (lane >> 4) * 8;
    unsigned short v[8];
    #pragma unroll
    for (int j = 0; j < 8; j++) v[j] = f2bf(W[(k0 + j) * NC + n]);
    *(uint4*)(Wb + (size_t)i * 8) = *(uint4*)v;
}

// ---------------- embed via MFMA ----------------
__global__ __launch_bounds__(256) void embed_mfma_kernel(const float* __restrict__ x,
                                                         const unsigned short* __restrict__ Wb,
                                                         const float* __restrict__ bias,
                                                         unsigned short* __restrict__ Jh) {
    int wave = threadIdx.x >> 6;
    int lane = threadIdx.x & 63;
    int tile = blockIdx.x * 4 + wave;
    if (tile >= NT) return;
    int m = lane & 15;
    int q = lane >> 4;
    const float* xr = x + (size_t)(tile * 16 + m) * 256 + q * 8;
    const unsigned short* bbase = Wb + (size_t)lane * 8;
    f32x4 acc[4];
    #pragma unroll
    for (int ct = 0; ct < 4; ct++) acc[ct] = (f32x4){0.f, 0.f, 0.f, 0.f};
    #pragma unroll
    for (int kb = 0; kb < 8; kb++) {
        float4 xa = *(const float4*)(xr + kb * 32);
        float4 xb = *(const float4*)(xr + kb * 32 + 4);
        unsigned short av[8];
        av[0] = f2bf(xa.x); av[1] = f2bf(xa.y); av[2] = f2bf(xa.z); av[3] = f2bf(xa.w);
        av[4] = f2bf(xb.x); av[5] = f2bf(xb.y); av[6] = f2bf(xb.z); av[7] = f2bf(xb.w);
        bf16x8 a = *(bf16x8*)av;
        #pragma unroll
        for (int ct = 0; ct < 4; ct++) {
            bf16x8 bfr = *(const bf16x8*)(bbase + (size_t)(ct * 8 + kb) * 512);
            acc[ct] = __builtin_amdgcn_mfma_f32_16x16x32_bf16(a, bfr, acc[ct], 0, 0, 0);
        }
    }
    #pragma unroll
    for (int ct = 0; ct < 4; ct++) {
        int col = ct * 16 + m;
        float bb = bias[col];
        #pragma unroll
        for (int r = 0; r < 4; r++) {
            float v = fmaxf(acc[ct][r] + bb, 0.f);
            Jh[(size_t)(tile * 16 + q * 4 + r) * LD + col] = f2bf(v);
        }
    }
}

// ---------------- sliced pull SPMM, bf16 source (one slice per LAUNCH) ----
// 4 lanes/row x 8 bf16 feats/lane (16B = one 64B line per edge with the
// other 3 lanes). Slice footprint NN*64B = 3.2MB -> L2-resident on every
// XCD because launches serialize on the stream (no placement assumption).
// NSL=2 -> conv0 (64-feat src), NSL=4 -> conv1 (128-feat src). src stride LD.
template <int NSL>
__global__ __launch_bounds__(256) void spmm_bf16_slice_kernel(
        const int* __restrict__ rp1, const unsigned int* __restrict__ ed1,
        const int* __restrict__ rp2, const unsigned int* __restrict__ ed2,
        const unsigned short* __restrict__ src, unsigned short* __restrict__ dst,
        int slice) {
    int g    = (blockIdx.x >= GBS) ? 1 : 0;
    int bx   = blockIdx.x - g * GBS;
    int wave = threadIdx.x >> 6;
    int lane = threadIdx.x & 63;
    int grp  = lane >> 2;                  // 16 rows per wave
    int sub  = lane & 3;                   // 4 lanes per row
    int row  = (bx * 4 + wave) * 16 + grp;
    const int*          rp = g ? rp2 : rp1;
    const unsigned int* ed = g ? ed2 : ed1;
    bool ok = row < NN;
    int beg = 0, end = 0;
    if (ok) { beg = rp[row]; end = rp[row + 1]; }

    f32x2 acc[4];
    #pragma unroll
    for (int u = 0; u < 4; u++) acc[u] = (f32x2){0.f, 0.f};
    const unsigned short* sbase = src + slice * 32 + sub * 8;

    int j = beg;
    for (; j + 8 <= end; j += 8) {
        unsigned int e[8];
        #pragma unroll
        for (int u = 0; u < 8; u++) e[u] = ed[j + u];
        uint4 s[8];
        #pragma unroll
        for (int u = 0; u < 8; u++) s[u] = *(const uint4*)(sbase + (size_t)(e[u] >> 16) * LD);
        #pragma unroll
        for (int u = 0; u < 8; u++) {
            float v = bfl(e[u]);
            f32x2 vv = (f32x2){v, v};
            acc[0] = pkfma(vv, bf2(s[u].x), acc[0]);
            acc[1] = pkfma(vv, bf2(s[u].y), acc[1]);
            acc[2] = pkfma(vv, bf2(s[u].z), acc[2]);
            acc[3] = pkfma(vv, bf2(s[u].w), acc[3]);
        }
    }
    for (; j < end; j++) {
        unsigned int e = ed[j];
        float v = bfl(e);
        f32x2 vv = (f32x2){v, v};
        uint4 s = *(const uint4*)(sbase + (size_t)(e >> 16) * LD);
        acc[0] = pkfma(vv, bf2(s.x), acc[0]);
        acc[1] = pkfma(vv, bf2(s.y), acc[1]);
        acc[2] = pkfma(vv, bf2(s.z), acc[2]);
        acc[3] = pkfma(vv, bf2(s.w), acc[3]);
    }

    if (ok) {
        unsigned short* dp = dst + (size_t)row * LD + g * (NSL * 32) + slice * 32 + sub * 8;
        uint4 o;
        o.x = pack2(acc[0][0], acc[0][1]); o.y = pack2(acc[1][0], acc[1][1]);
        o.z = pack2(acc[2][0], acc[2][1]); o.w = pack2(acc[3][0], acc[3][1]);
        *(uint4*)dp = o;
    }
}

// ---------------- sliced pull SPMM, fp8 source (conv2, one slice/LAUNCH) --
// 4 lanes/row x 16 fp8 feats/lane (16B). 4 slices of 64 feats; slice =
// one 64B line per row, 3.2MB footprint. src stride 256.
__global__ __launch_bounds__(256) void spmm_fp8_slice_kernel(
        const int* __restrict__ rp1, const unsigned int* __restrict__ ed1,
        const int* __restrict__ rp2, const unsigned int* __restrict__ ed2,
        const unsigned char* __restrict__ src8,   // [N, 256] fp8
        unsigned short* __restrict__ dst, int slice) {
    int g    = (blockIdx.x >= GBS) ? 1 : 0;
    int bx   = blockIdx.x - g * GBS;
    int wave = threadIdx.x >> 6;
    int lane = threadIdx.x & 63;
    int grp  = lane >> 2;
    int sub  = lane & 3;
    int row  = (bx * 4 + wave) * 16 + grp;
    const int*          rp = g ? rp2 : rp1;
    const unsigned int* ed = g ? ed2 : ed1;
    bool ok = row < NN;
    int beg = 0, end = 0;
    if (ok) { beg = rp[row]; end = rp[row + 1]; }

    f32x2 acc[8];
    #pragma unroll
    for (int u = 0; u < 8; u++) acc[u] = (f32x2){0.f, 0.f};
    const unsigned char* sbase = src8 + slice * 64 + sub * 16;

    int j = beg;
    for (; j + 8 <= end; j += 8) {
        unsigned int e[8];
        #pragma unroll
        for (int u = 0; u < 8; u++) e[u] = ed[j + u];
        uint4 s[8];
        #pragma unroll
        for (int u = 0; u < 8; u++) s[u] = *(const uint4*)(sbase + (size_t)(e[u] >> 16) * 256);
        #pragma unroll
        for (int u = 0; u < 8; u++) {
            float v = bfl(e[u]);
            f32x2 vv = (f32x2){v, v};
            acc[0] = pkfma(vv, __builtin_amdgcn_cvt_pk_f32_fp8(s[u].x, false), acc[0]);
            acc[1] = pkfma(vv, __builtin_amdgcn_cvt_pk_f32_fp8(s[u].x, true),  acc[1]);
            acc[2] = pkfma(vv, __builtin_amdgcn_cvt_pk_f32_fp8(s[u].y, false), acc[2]);
            acc[3] = pkfma(vv, __builtin_amdgcn_cvt_pk_f32_fp8(s[u].y, true),  acc[3]);
            acc[4] = pkfma(vv, __builtin_amdgcn_cvt_pk_f32_fp8(s[u].z, false), acc[4]);
            acc[5] = pkfma(vv, __builtin_amdgcn_cvt_pk_f32_fp8(s[u].z, true),  acc[5]);
            acc[6] = pkfma(vv, __builtin_amdgcn_cvt_pk_f32_fp8(s[u].w, false), acc[6]);
            acc[7] = pkfma(vv, __builtin_amdgcn_cvt_pk_f32_fp8(s[u].w, true),  acc[7]);
        }
    }
    for (; j < end; j++) {
        unsigned int e = ed[j];
        float v = bfl(e);
        f32x2 vv = (f32x2){v, v};
        uint4 s = *(const uint4*)(sbase + (size_t)(e >> 16) * 256);
        acc[0] = pkfma(vv, __builtin_amdgcn_cvt_pk_f32_fp8(s.x, false), acc[0]);
        acc[1] = pkfma(vv, __builtin_amdgcn_cvt_pk_f32_fp8(s.x, true),  acc[1]);
        acc[2] = pkfma(vv, __builtin_amdgcn_cvt_pk_f32_fp8(s.y, false), acc[2]);
        acc[3] = pkfma(vv, __builtin_amdgcn_cvt_pk_f32_fp8(s.y, true),  acc[3]);
        acc[4] = pkfma(vv, __builtin_amdgcn_cvt_pk_f32_fp8(s.z, false), acc[4]);
        acc[5] = pkfma(vv, __builtin_amdgcn_cvt_pk_f32_fp8(s.z, true),  acc[5]);
        acc[6] = pkfma(vv, __builtin_amdgcn_cvt_pk_f32_fp8(s.w, false), acc[6]);
        acc[7] = pkfma(vv, __builtin_amdgcn_cvt_pk_f32_fp8(s.w, true),  acc[7]);
    }

    if (ok) {
        unsigned short* dp = dst + (size_t)row * LD + g * 256 + slice * 64 + sub * 16;
        uint4 o1, o2;
        o1.x = pack2(acc[0][0], acc[0][1]); o1.y = pack2(acc[1][0], acc[1][1]);
        o1.z = pack2(acc[2][0], acc[2][1]); o1.w = pack2(acc[3][0], acc[3][1]);
        o2.x = pack2(acc[4][0], acc[4][1]); o2.y = pack2(acc[5][0], acc[5][1]);
        o2.z = pack2(acc[6][0], acc[6][1]); o2.w = pack2(acc[7][0], acc[7][1]);
        *(uint4*)dp = o1;
        *(uint4*)(dp + 8) = o2;
    }
}

// ---------------- BN stats / finalize / apply ----------------
template <int F>
__global__ __launch_bounds__(256) void bn_stats_kernel(const unsigned short* __restrict__ c,
                                                       float* sum, float* sumsq) {
    constexpr int SL = 256 / F;
    int f  = threadIdx.x % F;
    int sl = threadIdx.x / F;
    float s = 0.f, ss = 0.f;
    for (int r = blockIdx.x * SL + sl; r < NN; r += gridDim.x * SL) {
        float v = bf2f(c[(size_t)r * LD + f]);
        s += v; ss += v * v;
    }
    __shared__ float ls[256], lss[256];
    ls[threadIdx.x] = s; lss[threadIdx.x] = ss;
    __syncthreads();
    if (sl == 0) {
        #pragma unroll
        for (int u = 1; u < SL; u++) { s += ls[f + u * F]; ss += lss[f + u * F]; }
        atomicAdd(&sum[f], s);
        atomicAdd(&sumsq[f], ss);
    }
}

__global__ void bn_finalize_kernel(const float* sum, const float* sumsq, const float* __restrict__ gamma,
                                   const float* __restrict__ beta, float* scale, float* shift, int F) {
    int f = blockIdx.x * blockDim.x + threadIdx.x;
    if (f >= F) return;
    float m   = sum[f] * (1.0f / NN);
    float var = sumsq[f] * (1.0f / NN) - m * m;
    float sc  = gamma[f] * rsqrtf(var + 1e-5f);
    scale[f] = sc;
    shift[f] = beta[f] - m * sc;
}

template <int F>
__global__ __launch_bounds__(256) void bn_apply_kernel(unsigned short* __restrict__ c,
                                                       const float* __restrict__ scale,
                                                       const float* __restrict__ shift) {
    constexpr int FV = F / 4;
    int idx  = blockIdx.x * 256 + threadIdx.x;
    int node = idx / FV;
    int fo   = (idx % FV) * 4;
    if (node >= NN) return;
    unsigned short* p = c + (size_t)node * LD + fo;
    uint2 v = *(uint2*)p;
    float a0 = bfl(v.x), a1 = bfh(v.x), a2 = bfl(v.y), a3 = bfh(v.y);
    float4 sc = *(const float4*)(scale + fo);
    float4 sh = *(const float4*)(shift + fo);
    a0 = fmaf(a0, sc.x, sh.x);
    a1 = fmaf(a1, sc.y, sh.y);
    a2 = fmaf(a2, sc.z, sh.z);
    a3 = fmaf(a3, sc.w, sh.w);
    v.x = pack2(a0, a1); v.y = pack2(a2, a3);
    *(uint2*)p = v;
}

// BN apply on c1 (F=256): bf16 in-place AND fp8 copy for conv2's gather
__global__ __launch_bounds__(256) void bn_apply_fp8_kernel(unsigned short* __restrict__ c,
                                                           unsigned char* __restrict__ c8,
                                                           const float* __restrict__ scale,
                                                           const float* __restrict__ shift) {
    int idx  = blockIdx.x * 256 + threadIdx.x;
    int node = idx >> 6;
    int fo   = (idx & 63) * 4;
    if (node >= NN) return;
    unsigned short* p = c + (size_t)node * LD + fo;
    uint2 v = *(uint2*)p;
    float a0 = bfl(v.x), a1 = bfh(v.x), a2 = bfl(v.y), a3 = bfh(v.y);
    float4 sc = *(const float4*)(scale + fo);
    float4 sh = *(const float4*)(shift + fo);
    a0 = fmaf(a0, sc.x, sh.x);
    a1 = fmaf(a1, sc.y, sh.y);
    a2 = fmaf(a2, sc.z, sh.z);
    a3 = fmaf(a3, sc.w, sh.w);
    v.x = pack2(a0, a1); v.y = pack2(a2, a3);
    *(uint2*)p = v;
    *(unsigned int*)(c8 + (size_t)node * 256 + fo) = packfp8(a0, a1, a2, a3);
}

// ---------------- head GEMM via MFMA ----------------
__global__ __launch_bounds__(256) void head_mfma_kernel(const unsigned short* __restrict__ Jh,
                                                        const unsigned short* __restrict__ Wb,
                                                        const float* __restrict__ b,
                                                        float* __restrict__ out) {
    int wave = threadIdx.x >> 6;
    int lane = threadIdx.x & 63;
    int tile = blockIdx.x * 4 + wave;
    if (tile >= NT) return;
    int m = lane & 15;
    int q = lane >> 4;
    const unsigned short* arow  = Jh + (size_t)(tile * 16 + m) * LD + q * 8;
    const unsigned short* bbase = Wb + (size_t)lane * 8;
    f32x4 acc0 = {0.f, 0.f, 0.f, 0.f};
    f32x4 acc1 = {0.f, 0.f, 0.f, 0.f};
    #pragma unroll 5
    for (int kb = 0; kb < 30; kb++) {
        bf16x8 a  = *(const bf16x8*)(arow + kb * 32);
        bf16x8 b0 = *(const bf16x8*)(bbase + (size_t)kb * 512);
        bf16x8 b1 = *(const bf16x8*)(bbase + (size_t)(30 + kb) * 512);
        acc0 = __builtin_amdgcn_mfma_f32_16x16x32_bf16(a, b0, acc0, 0, 0, 0);
        acc1 = __builtin_amdgcn_mfma_f32_16x16x32_bf16(a, b1, acc1, 0, 0, 0);
    }
    int col = m;
    float b0 = b[col], b1 = b[16 + col];
    #pragma unroll
    for (int r = 0; r < 4; r++) {
        float* op = out + (size_t)(tile * 16 + q * 4 + r) * 32 + col;
        op[0]  = acc0[r] + b0;
        op[16] = acc1[r] + b1;
    }
}

// ---------------- launch ----------------

extern "C" void kernel_launch(void* const* d_in, const int* in_sizes, int n_in,
                              void* d_out, int out_size, void* d_ws, size_t ws_size,
                              hipStream_t stream) {
    const float* x      = (const float*)d_in[0];
    const int*   e1_row = (const int*)d_in[1];
    const int*   e1_col = (const int*)d_in[2];
    const float* e1_val = (const float*)d_in[3];
    const int*   e2_row = (const int*)d_in[4];
    const int*   e2_col = (const int*)d_in[5];
    const float* e2_val = (const float*)d_in[6];
    const float* W_emb  = (const float*)d_in[7];
    const float* b_emb  = (const float*)d_in[8];
    const float* bn0_g  = (const float*)d_in[9];
    const float* bn0_b  = (const float*)d_in[10];
    const float* bn1_g  = (const float*)d_in[11];
    const float* bn1_b  = (const float*)d_in[12];
    const float* W_head = (const float*)d_in[13];
    const float* b_head = (const float*)d_in[14];
    float* out = (float*)d_out;

    char* ws = (char*)d_ws;
    auto alloc = [&](size_t bytes) -> char* {
        char* p = ws;
        ws += (bytes + 255) & ~(size_t)255;
        return p;
    };
    int*   rp1   = (int*)alloc((NN + 1) * 4);
    int*   rp2   = (int*)alloc((NN + 1) * 4);
    int*   bc1   = (int*)alloc((size_t)G1B * NBKT * 4);
    int*   bc2   = (int*)alloc((size_t)G2B * NBKT * 4);
    unsigned int* Ed1 = (unsigned int*)alloc((size_t)E1N * 4);
    unsigned int* Ed2 = (unsigned int*)alloc((size_t)E2N * 4);
    float* stats = (float*)alloc(1536 * 4);
    unsigned short* Wbh  = (unsigned short*)alloc(3840 * 8 * 2);
    unsigned short* Wbe  = (unsigned short*)alloc(2048 * 8 * 2);
    unsigned char*  C1f8 = (unsigned char*)alloc((size_t)NN * 256);
    unsigned short* Jh   = (unsigned short*)alloc((size_t)NN * LD * 2);
    // temp 8B records alias Jh (dead until embed writes it)
    uint2* T1 = (uint2*)Jh;
    uint2* T2 = T1 + E1N;

    float* sum0   = stats;        float* sq0    = stats + 128;
    float* sum1   = stats + 256;  float* sq1    = stats + 512;
    float* scale0 = stats + 768;  float* shift0 = stats + 896;
    float* scale1 = stats + 1024; float* shift1 = stats + 1280;

    // CSR build (LDS counting sort) + weight packs
    zero_kernel<<<3, 256, 0, stream>>>(stats, 768);
    bucket_count_kernel<<<G1B + G2B, 256, 0, stream>>>(e1_row, e2_row, bc1, bc2);
    bucket_scan_kernel<<<1, 512, 0, stream>>>(bc1, bc2);
    bucket_place_kernel<<<G1B + G2B, 256, 0, stream>>>(e1_row, e1_col, e1_val,
                                                       e2_row, e2_col, e2_val, bc1, bc2, T1, T2);
    bucket_sort_kernel<<<2 * NBKT, 256, 0, stream>>>(bc1, T1, rp1, Ed1, bc2, T2, rp2, Ed2);
    packw_kernel<<<15, 256, 0, stream>>>(W_head, Wbh, 32, 30, 3840);
    packw_kernel<<<8, 256, 0, stream>>>(W_emb, Wbe, 64, 8, 2048);

    // embed -> Jh[:,0:64) (MFMA)  (T1/T2 dead from here on)
    embed_mfma_kernel<<<(NT + 3) / 4, 256, 0, stream>>>(x, Wbe, b_emb, Jh);

    // conv0 (bf16 h, 2 serialized slices x 32 feats) -> Jh[:,64:192), then BN
    for (int s = 0; s < 2; s++)
        spmm_bf16_slice_kernel<2><<<2 * GBS, 256, 0, stream>>>(rp1, Ed1, rp2, Ed2, Jh, Jh + 64, s);
    bn_stats_kernel<128><<<512, 256, 0, stream>>>(Jh + 64, sum0, sq0);
    bn_finalize_kernel<<<1, 128, 0, stream>>>(sum0, sq0, bn0_g, bn0_b, scale0, shift0, 128);
    bn_apply_kernel<128><<<(NN * 32 + 255) / 256, 256, 0, stream>>>(Jh + 64, scale0, shift0);

    // conv1 (bf16 c0', 4 serialized slices x 32 feats) -> Jh[:,192:448), then BN + fp8 copy
    for (int s = 0; s < 4; s++)
        spmm_bf16_slice_kernel<4><<<2 * GBS, 256, 0, stream>>>(rp1, Ed1, rp2, Ed2, Jh + 64, Jh + 192, s);
    bn_stats_kernel<256><<<512, 256, 0, stream>>>(Jh + 192, sum1, sq1);
    bn_finalize_kernel<<<1, 256, 0, stream>>>(sum1, sq1, bn1_g, bn1_b, scale1, shift1, 256);
    bn_apply_fp8_kernel<<<(NN * 64 + 255) / 256, 256, 0, stream>>>(Jh + 192, C1f8, scale1, shift1);

    // conv2 (fp8 c1', 4 serialized slices x 64 feats) -> Jh[:,448:960)
    for (int s = 0; s < 4; s++)
        spmm_fp8_slice_kernel<<<2 * GBS, 256, 0, stream>>>(rp1, Ed1, rp2, Ed2, C1f8, Jh + 448, s);

    // head (MFMA)
    head_mfma_kernel<<<(NT + 3) / 4, 256, 0, stream>>>(Jh, Wbh, b_head, out);
}

// Round 6
// 632.608 us; speedup vs baseline: 1.0139x; 1.0139x over previous
//
#include <hip/hip_runtime.h>

// H2GCN forward, bf16 activations in fused Jh[N,960]:
//   cols [0,64)=h [64,192)=c0 [192,448)=c1 [448,960)=c2.
// CSR build = two-level LDS counting sort (r10).
// r12: v_pk_fma_f32 + 16B gathers + 8-edge batches (543.7us verified).
// r13/r14 (XCD-pinned CONCURRENT slices): FAILED (FETCH 230->417MB).
// r15: column-grouped edges (sort key = localrow*7 + col>>13): 533.9us,
//   FETCH 230->212MB. KEPT.
// r16 (SERIALIZED per-slice launches): REGRESSED 534->641 (edge re-reads +
//   16x launch overhead). REVERTED. Verdict after r13/r15/r16: the ~3.5TB/s
//   miss-path rate for the random gather is structural; stop chasing it.
// r17: CSR-build occupancy fix. bucket_place was the #1 dispatch (56.5us,
//   Occupancy 9.8%, HBM 1TB/s): grid was G1B+G2B=294 blocks on 256 CUs ->
//   grid-starved. CHUNK 8192->2048 (G1B=391,G2B=782 -> 1173 blocks, ~57%
//   occupancy ceiling). bucket_count shares the fix. bucket_scan loops 4x
//   longer (streaming, single block) — small known cost.
// fp8 ONLY at the leaf conv (r11: fp8 earlier cascades, absmax FAIL).
// Embed + Head: MFMA 16x16x32 bf16, weights pre-packed to B-fragment layout.

#define NN  50000
#define E1N 800000
#define E2N 1600000
#define LD  960
#define NT  3125         // 16-node tiles
#define NBKT 391         // 128-row buckets
#define CHUNK 2048
#define G1B 391          // ceil(E1N/CHUNK)
#define G2B 782          // ceil(E2N/CHUNK)
#define NCG 7            // column groups of 8192 nodes

typedef short bf16x8 __attribute__((ext_vector_type(8)));
typedef float f32x4  __attribute__((ext_vector_type(4)));
typedef float f32x2  __attribute__((ext_vector_type(2)));

__device__ __forceinline__ float bfl(unsigned int w) { return __uint_as_float(w << 16); }
__device__ __forceinline__ float bfh(unsigned int w) { return __uint_as_float(w & 0xFFFF0000u); }
__device__ __forceinline__ float bf2f(unsigned short u) { return __uint_as_float(((unsigned int)u) << 16); }
__device__ __forceinline__ unsigned short f2bf(float f) {         // RNE
    unsigned int u = __float_as_uint(f);
    u += 0x7FFFu + ((u >> 16) & 1u);
    return (unsigned short)(u >> 16);
}
__device__ __forceinline__ unsigned int pack2(float a, float b) {
    return (unsigned int)f2bf(a) | ((unsigned int)f2bf(b) << 16);
}
__device__ __forceinline__ unsigned int packfp8(float a, float b, float c, float d) {
    int w = __builtin_amdgcn_cvt_pk_fp8_f32(a, b, 0, false);
    w     = __builtin_amdgcn_cvt_pk_fp8_f32(c, d, w, true);
    return (unsigned int)w;
}
// packed f32 fma (v_pk_fma_f32 on gfx950); identical per-lane rounding to fmaf
__device__ __forceinline__ f32x2 pkfma(f32x2 a, f32x2 b, f32x2 c) {
#if __has_builtin(__builtin_elementwise_fma)
    return __builtin_elementwise_fma(a, b, c);
#else
    return (f32x2){fmaf(a[0], b[0], c[0]), fmaf(a[1], b[1], c[1])};
#endif
}
// bf16 pair (packed in a u32) -> f32x2 {lo, hi}
__device__ __forceinline__ f32x2 bf2(unsigned int w) {
    return (f32x2){bfl(w), bfh(w)};
}

// ---------------- CSR build ----------------

__global__ __launch_bounds__(256) void zero_kernel(float* c, int nc) {
    int i = blockIdx.x * 256 + threadIdx.x;
    if (i < nc) c[i] = 0.f;
}

__global__ __launch_bounds__(256) void bucket_count_kernel(const int* __restrict__ r1,
                                                           const int* __restrict__ r2,
                                                           int* __restrict__ bc1, int* __restrict__ bc2) {
    __shared__ int cnt[NBKT];
    for (int t = threadIdx.x; t < NBKT; t += 256) cnt[t] = 0;
    __syncthreads();
    int blk = blockIdx.x;
    const int* r; int base, lim; int* bc;
    if (blk < G1B) { r = r1; base = blk * CHUNK; lim = min(base + CHUNK, E1N); bc = bc1 + blk * NBKT; }
    else { int b2 = blk - G1B; r = r2; base = b2 * CHUNK; lim = min(base + CHUNK, E2N); bc = bc2 + b2 * NBKT; }
    for (int i = base + threadIdx.x; i < lim; i += 256)
        atomicAdd(&cnt[r[i] >> 7], 1);
    __syncthreads();
    for (int t = threadIdx.x; t < NBKT; t += 256) bc[t] = cnt[t];
}

__global__ __launch_bounds__(512) void bucket_scan_kernel(int* __restrict__ bc1, int* __restrict__ bc2) {
    __shared__ int s[512];
    int t = threadIdx.x;
    int tot1 = 0, tot2 = 0;
    if (t < NBKT) {
        for (int b = 0; b < G1B; b++) tot1 += bc1[b * NBKT + t];
        for (int b = 0; b < G2B; b++) tot2 += bc2[b * NBKT + t];
    }
    s[t] = (t < NBKT) ? tot1 : 0;
    __syncthreads();
    for (int off = 1; off < 512; off <<= 1) {
        int v = (t >= off) ? s[t - off] : 0;
        __syncthreads(); s[t] += v; __syncthreads();
    }
    int base1 = ((t < NBKT) ? s[t] : 0) - tot1;
    __syncthreads();
    s[t] = (t < NBKT) ? tot2 : 0;
    __syncthreads();
    for (int off = 1; off < 512; off <<= 1) {
        int v = (t >= off) ? s[t - off] : 0;
        __syncthreads(); s[t] += v; __syncthreads();
    }
    int base2 = ((t < NBKT) ? s[t] : 0) - tot2;
    if (t < NBKT) {
        int run = base1;
        for (int b = 0; b < G1B; b++) { int v = bc1[b * NBKT + t]; bc1[b * NBKT + t] = run; run += v; }
        run = base2;
        for (int b = 0; b < G2B; b++) { int v = bc2[b * NBKT + t]; bc2[b * NBKT + t] = run; run += v; }
    }
}

__global__ __launch_bounds__(256) void bucket_place_kernel(
        const int* __restrict__ r1, const int* __restrict__ c1, const float* __restrict__ v1,
        const int* __restrict__ r2, const int* __restrict__ c2, const float* __restrict__ v2,
        const int* __restrict__ bc1, const int* __restrict__ bc2,
        uint2* __restrict__ T1, uint2* __restrict__ T2) {
    __shared__ int pos[NBKT];
    int blk = blockIdx.x;
    const int *r, *c; const float* v; int base, lim; const int* bc; uint2* T;
    if (blk < G1B) { r = r1; c = c1; v = v1; base = blk * CHUNK; lim = min(base + CHUNK, E1N);
                     bc = bc1 + blk * NBKT; T = T1; }
    else { int b2 = blk - G1B; r = r2; c = c2; v = v2; base = b2 * CHUNK; lim = min(base + CHUNK, E2N);
           bc = bc2 + b2 * NBKT; T = T2; }
    for (int t = threadIdx.x; t < NBKT; t += 256) pos[t] = bc[t];
    __syncthreads();
    for (int i = base + threadIdx.x; i < lim; i += 256) {
        int row = r[i];
        int p = atomicAdd(&pos[row >> 7], 1);
        T[p] = make_uint2(((unsigned)c[i] << 16) | (unsigned)row, __float_as_uint(v[i]));
    }
}

// Second-level sort: key = localrow*NCG + colgroup (col>>13). Produces CSR
// where each row's edges are grouped by ascending 8192-node column group.
__global__ __launch_bounds__(256) void bucket_sort_kernel(
        const int* __restrict__ bb1, const uint2* __restrict__ T1, int* __restrict__ rp1, unsigned int* __restrict__ Ed1,
        const int* __restrict__ bb2, const uint2* __restrict__ T2, int* __restrict__ rp2, unsigned int* __restrict__ Ed2) {
    int b = blockIdx.x % NBKT;
    int g = blockIdx.x / NBKT;
    const int* bb = g ? bb2 : bb1;
    const uint2* T = g ? T2 : T1;
    int* rp = g ? rp2 : rp1;
    unsigned int* Ed = g ? Ed2 : Ed1;
    int EN = g ? E2N : E1N;
    int beg = bb[b];
    int end = (b == NBKT - 1) ? EN : bb[b + 1];
    int R0 = b * 128;
    int nrows = min(128, NN - R0);
    // keys: 0 .. 128*NCG-1 = 895. counts stored at cnt[key+1]; cnt[0]=0.
    __shared__ int cnt[1024];
    __shared__ int cur[896];
    __shared__ int ps[256];
    int t = threadIdx.x;
    for (int i = t; i < 1024; i += 256) cnt[i] = 0;
    __syncthreads();
    for (int i = beg + t; i < end; i += 256) {
        unsigned int x = T[i].x;
        int lr = (x & 0xFFFFu) & 127;
        int cg = (int)(x >> 29);            // (col>>13): col in bits [16,32) -> >>29
        atomicAdd(&cnt[lr * NCG + cg + 1], 1);
    }
    __syncthreads();
    // inclusive scan of cnt[0..1023], 4 elems/thread
    int b0 = t * 4;
    int c0 = cnt[b0], c1 = cnt[b0 + 1], c2 = cnt[b0 + 2], c3 = cnt[b0 + 3];
    int s1 = c0 + c1, s2 = s1 + c2, s3 = s2 + c3;
    ps[t] = s3;
    __syncthreads();
    for (int off = 1; off < 256; off <<= 1) {
        int v = (t >= off) ? ps[t - off] : 0;
        __syncthreads(); ps[t] += v; __syncthreads();
    }
    int base = (t > 0) ? ps[t - 1] : 0;
    cnt[b0] = base + c0; cnt[b0 + 1] = base + s1;
    cnt[b0 + 2] = base + s2; cnt[b0 + 3] = base + s3;
    __syncthreads();
    // cnt[k] (inclusive scan at index k) == exclusive prefix for key k
    for (int k = t; k < 896; k += 256) cur[k] = beg + cnt[k];
    if (t < nrows) rp[R0 + t] = beg + cnt[t * NCG];
    if (b == NBKT - 1 && t == 0) rp[NN] = end;
    __syncthreads();
    for (int i = beg + t; i < end; i += 256) {
        uint2 rec = T[i];
        int lr = (rec.x & 0xFFFFu) & 127;
        int cg = (int)(rec.x >> 29);
        int p = atomicAdd(&cur[lr * NCG + cg], 1);
        Ed[p] = (rec.x & 0xFFFF0000u) | (unsigned)f2bf(__uint_as_float(rec.y));
    }
}

// ---------------- weight -> bf16 B-fragment pack ----------------
__global__ __launch_bounds__(256) void packw_kernel(const float* __restrict__ W, unsigned short* __restrict__ Wb,
                                                    int NC, int kbs, int total) {
    int i = blockIdx.x * 256 + threadIdx.x;
    if (i >= total) return;
    int lane  = i & 63;
    int kb    = (i >> 6) % kbs;
    int ctile = i / (kbs * 64);
    int n  = ctile * 16 + (lane & 15);
    int k0 = kb * 32 + (lane >> 4) * 8;
    unsigned short v[8];
    #pragma unroll
    for (int j = 0; j < 8; j++) v[j] = f2bf(W[(k0 + j) * NC + n]);
    *(uint4*)(Wb + (size_t)i * 8) = *(uint4*)v;
}

// ---------------- embed via MFMA ----------------
__global__ __launch_bounds__(256) void embed_mfma_kernel(const float* __restrict__ x,
                                                         const unsigned short* __restrict__ Wb,
                                                         const float* __restrict__ bias,
                                                         unsigned short* __restrict__ Jh) {
    int wave = threadIdx.x >> 6;
    int lane = threadIdx.x & 63;
    int tile = blockIdx.x * 4 + wave;
    if (tile >= NT) return;
    int m = lane & 15;
    int q = lane >> 4;
    const float* xr = x + (size_t)(tile * 16 + m) * 256 + q * 8;
    const unsigned short* bbase = Wb + (size_t)lane * 8;
    f32x4 acc[4];
    #pragma unroll
    for (int ct = 0; ct < 4; ct++) acc[ct] = (f32x4){0.f, 0.f, 0.f, 0.f};
    #pragma unroll
    for (int kb = 0; kb < 8; kb++) {
        float4 xa = *(const float4*)(xr + kb * 32);
        float4 xb = *(const float4*)(xr + kb * 32 + 4);
        unsigned short av[8];
        av[0] = f2bf(xa.x); av[1] = f2bf(xa.y); av[2] = f2bf(xa.z); av[3] = f2bf(xa.w);
        av[4] = f2bf(xb.x); av[5] = f2bf(xb.y); av[6] = f2bf(xb.z); av[7] = f2bf(xb.w);
        bf16x8 a = *(bf16x8*)av;
        #pragma unroll
        for (int ct = 0; ct < 4; ct++) {
            bf16x8 bfr = *(const bf16x8*)(bbase + (size_t)(ct * 8 + kb) * 512);
            acc[ct] = __builtin_amdgcn_mfma_f32_16x16x32_bf16(a, bfr, acc[ct], 0, 0, 0);
        }
    }
    #pragma unroll
    for (int ct = 0; ct < 4; ct++) {
        int col = ct * 16 + m;
        float bb = bias[col];
        #pragma unroll
        for (int r = 0; r < 4; r++) {
            float v = fmaxf(acc[ct][r] + bb, 0.f);
            Jh[(size_t)(tile * 16 + q * 4 + r) * LD + col] = f2bf(v);
        }
    }
}

// ---------------- pull SPMM, bf16 source, 8 feats/lane, 16B loads ----------------
// LPR=8  -> conv0 (64-feat source), LPR=16 -> conv1 (128-feat source)
template <int LPR>
__global__ __launch_bounds__(256) void spmm_bf16x8_kernel(
        const int* __restrict__ rp1, const unsigned int* __restrict__ ed1,
        const int* __restrict__ rp2, const unsigned int* __restrict__ ed2,
        const unsigned short* __restrict__ src, unsigned short* __restrict__ dst) {
    constexpr int ROWS = 64 / LPR;
    constexpr int SRCF = LPR * 8;
    constexpr int RPB  = ROWS * 4;
    constexpr int GB   = (NN + RPB - 1) / RPB;
    int g    = (blockIdx.x >= GB) ? 1 : 0;
    int bx   = blockIdx.x - g * GB;
    int wave = threadIdx.x >> 6;
    int lane = threadIdx.x & 63;
    int grp  = lane / LPR;
    int sub  = lane % LPR;
    int row  = (bx * 4 + wave) * ROWS + grp;
    const int*          rp = g ? rp2 : rp1;
    const unsigned int* ed = g ? ed2 : ed1;
    bool ok = row < NN;
    int beg = 0, end = 0;
    if (ok) { beg = rp[row]; end = rp[row + 1]; }

    f32x2 acc[4];
    #pragma unroll
    for (int u = 0; u < 4; u++) acc[u] = (f32x2){0.f, 0.f};
    const unsigned short* sbase = src + sub * 8;

    int j = beg;
    for (; j + 8 <= end; j += 8) {
        unsigned int e[8];
        #pragma unroll
        for (int u = 0; u < 8; u++) e[u] = ed[j + u];
        uint4 s[8];
        #pragma unroll
        for (int u = 0; u < 8; u++) s[u] = *(const uint4*)(sbase + (size_t)(e[u] >> 16) * LD);
        #pragma unroll
        for (int u = 0; u < 8; u++) {
            float v = bfl(e[u]);
            f32x2 vv = (f32x2){v, v};
            acc[0] = pkfma(vv, bf2(s[u].x), acc[0]);
            acc[1] = pkfma(vv, bf2(s[u].y), acc[1]);
            acc[2] = pkfma(vv, bf2(s[u].z), acc[2]);
            acc[3] = pkfma(vv, bf2(s[u].w), acc[3]);
        }
    }
    for (; j < end; j++) {
        unsigned int e = ed[j];
        float v = bfl(e);
        f32x2 vv = (f32x2){v, v};
        uint4 s = *(const uint4*)(sbase + (size_t)(e >> 16) * LD);
        acc[0] = pkfma(vv, bf2(s.x), acc[0]);
        acc[1] = pkfma(vv, bf2(s.y), acc[1]);
        acc[2] = pkfma(vv, bf2(s.z), acc[2]);
        acc[3] = pkfma(vv, bf2(s.w), acc[3]);
    }

    if (ok) {
        unsigned short* dp = dst + (size_t)row * LD + g * SRCF + sub * 8;
        uint4 o;
        o.x = pack2(acc[0][0], acc[0][1]); o.y = pack2(acc[1][0], acc[1][1]);
        o.z = pack2(acc[2][0], acc[2][1]); o.w = pack2(acc[3][0], acc[3][1]);
        *(uint4*)dp = o;
    }
}

// ---------------- pull SPMM, fp8 source, 16 feats/lane, 16B loads (conv2) ----------------
template <int LPR>
__global__ __launch_bounds__(256) void spmm_fp8x16_kernel(
        const int* __restrict__ rp1, const unsigned int* __restrict__ ed1,
        const int* __restrict__ rp2, const unsigned int* __restrict__ ed2,
        const unsigned char* __restrict__ src8,   // [N, LPR*16] fp8
        unsigned short* __restrict__ dst) {
    constexpr int ROWS = 64 / LPR;     // 4
    constexpr int SRCF = LPR * 16;     // 256
    constexpr int RPB  = ROWS * 4;
    constexpr int GB   = (NN + RPB - 1) / RPB;
    int g    = (blockIdx.x >= GB) ? 1 : 0;
    int bx   = blockIdx.x - g * GB;
    int wave = threadIdx.x >> 6;
    int lane = threadIdx.x & 63;
    int grp  = lane / LPR;
    int sub  = lane % LPR;
    int row  = (bx * 4 + wave) * ROWS + grp;
    const int*          rp = g ? rp2 : rp1;
    const unsigned int* ed = g ? ed2 : ed1;
    bool ok = row < NN;
    int beg = 0, end = 0;
    if (ok) { beg = rp[row]; end = rp[row + 1]; }

    f32x2 acc[8];
    #pragma unroll
    for (int u = 0; u < 8; u++) acc[u] = (f32x2){0.f, 0.f};
    const unsigned char* sbase = src8 + sub * 16;

    int j = beg;
    for (; j + 8 <= end; j += 8) {
        unsigned int e[8];
        #pragma unroll
        for (int u = 0; u < 8; u++) e[u] = ed[j + u];
        uint4 s[8];
        #pragma unroll
        for (int u = 0; u < 8; u++) s[u] = *(const uint4*)(sbase + (size_t)(e[u] >> 16) * SRCF);
        #pragma unroll
        for (int u = 0; u < 8; u++) {
            float v = bfl(e[u]);
            f32x2 vv = (f32x2){v, v};
            acc[0] = pkfma(vv, __builtin_amdgcn_cvt_pk_f32_fp8(s[u].x, false), acc[0]);
            acc[1] = pkfma(vv, __builtin_amdgcn_cvt_pk_f32_fp8(s[u].x, true),  acc[1]);
            acc[2] = pkfma(vv, __builtin_amdgcn_cvt_pk_f32_fp8(s[u].y, false), acc[2]);
            acc[3] = pkfma(vv, __builtin_amdgcn_cvt_pk_f32_fp8(s[u].y, true),  acc[3]);
            acc[4] = pkfma(vv, __builtin_amdgcn_cvt_pk_f32_fp8(s[u].z, false), acc[4]);
            acc[5] = pkfma(vv, __builtin_amdgcn_cvt_pk_f32_fp8(s[u].z, true),  acc[5]);
            acc[6] = pkfma(vv, __builtin_amdgcn_cvt_pk_f32_fp8(s[u].w, false), acc[6]);
            acc[7] = pkfma(vv, __builtin_amdgcn_cvt_pk_f32_fp8(s[u].w, true),  acc[7]);
        }
    }
    for (; j < end; j++) {
        unsigned int e = ed[j];
        float v = bfl(e);
        f32x2 vv = (f32x2){v, v};
        uint4 s = *(const uint4*)(sbase + (size_t)(e >> 16) * SRCF);
        acc[0] = pkfma(vv, __builtin_amdgcn_cvt_pk_f32_fp8(s.x, false), acc[0]);
        acc[1] = pkfma(vv, __builtin_amdgcn_cvt_pk_f32_fp8(s.x, true),  acc[1]);
        acc[2] = pkfma(vv, __builtin_amdgcn_cvt_pk_f32_fp8(s.y, false), acc[2]);
        acc[3] = pkfma(vv, __builtin_amdgcn_cvt_pk_f32_fp8(s.y, true),  acc[3]);
        acc[4] = pkfma(vv, __builtin_amdgcn_cvt_pk_f32_fp8(s.z, false), acc[4]);
        acc[5] = pkfma(vv, __builtin_amdgcn_cvt_pk_f32_fp8(s.z, true),  acc[5]);
        acc[6] = pkfma(vv, __builtin_amdgcn_cvt_pk_f32_fp8(s.w, false), acc[6]);
        acc[7] = pkfma(vv, __builtin_amdgcn_cvt_pk_f32_fp8(s.w, true),  acc[7]);
    }

    if (ok) {
        unsigned short* dp = dst + (size_t)row * LD + g * SRCF + sub * 16;
        uint4 o1, o2;
        o1.x = pack2(acc[0][0], acc[0][1]); o1.y = pack2(acc[1][0], acc[1][1]);
        o1.z = pack2(acc[2][0], acc[2][1]); o1.w = pack2(acc[3][0], acc[3][1]);
        o2.x = pack2(acc[4][0], acc[4][1]); o2.y = pack2(acc[5][0], acc[5][1]);
        o2.z = pack2(acc[6][0], acc[6][1]); o2.w = pack2(acc[7][0], acc[7][1]);
        *(uint4*)dp = o1;
        *(uint4*)(dp + 8) = o2;
    }
}

// ---------------- BN stats / finalize / apply ----------------
template <int F>
__global__ __launch_bounds__(256) void bn_stats_kernel(const unsigned short* __restrict__ c,
                                                       float* sum, float* sumsq) {
    constexpr int SL = 256 / F;
    int f  = threadIdx.x % F;
    int sl = threadIdx.x / F;
    float s = 0.f, ss = 0.f;
    for (int r = blockIdx.x * SL + sl; r < NN; r += gridDim.x * SL) {
        float v = bf2f(c[(size_t)r * LD + f]);
        s += v; ss += v * v;
    }
    __shared__ float ls[256], lss[256];
    ls[threadIdx.x] = s; lss[threadIdx.x] = ss;
    __syncthreads();
    if (sl == 0) {
        #pragma unroll
        for (int u = 1; u < SL; u++) { s += ls[f + u * F]; ss += lss[f + u * F]; }
        atomicAdd(&sum[f], s);
        atomicAdd(&sumsq[f], ss);
    }
}

__global__ void bn_finalize_kernel(const float* sum, const float* sumsq, const float* __restrict__ gamma,
                                   const float* __restrict__ beta, float* scale, float* shift, int F) {
    int f = blockIdx.x * blockDim.x + threadIdx.x;
    if (f >= F) return;
    float m   = sum[f] * (1.0f / NN);
    float var = sumsq[f] * (1.0f / NN) - m * m;
    float sc  = gamma[f] * rsqrtf(var + 1e-5f);
    scale[f] = sc;
    shift[f] = beta[f] - m * sc;
}

template <int F>
__global__ __launch_bounds__(256) void bn_apply_kernel(unsigned short* __restrict__ c,
                                                       const float* __restrict__ scale,
                                                       const float* __restrict__ shift) {
    constexpr int FV = F / 4;
    int idx  = blockIdx.x * 256 + threadIdx.x;
    int node = idx / FV;
    int fo   = (idx % FV) * 4;
    if (node >= NN) return;
    unsigned short* p = c + (size_t)node * LD + fo;
    uint2 v = *(uint2*)p;
    float a0 = bfl(v.x), a1 = bfh(v.x), a2 = bfl(v.y), a3 = bfh(v.y);
    float4 sc = *(const float4*)(scale + fo);
    float4 sh = *(const float4*)(shift + fo);
    a0 = fmaf(a0, sc.x, sh.x);
    a1 = fmaf(a1, sc.y, sh.y);
    a2 = fmaf(a2, sc.z, sh.z);
    a3 = fmaf(a3, sc.w, sh.w);
    v.x = pack2(a0, a1); v.y = pack2(a2, a3);
    *(uint2*)p = v;
}

// BN apply on c1 (F=256): bf16 in-place AND fp8 copy for conv2's gather
__global__ __launch_bounds__(256) void bn_apply_fp8_kernel(unsigned short* __restrict__ c,
                                                           unsigned char* __restrict__ c8,
                                                           const float* __restrict__ scale,
                                                           const float* __restrict__ shift) {
    int idx  = blockIdx.x * 256 + threadIdx.x;
    int node = idx >> 6;
    int fo   = (idx & 63) * 4;
    if (node >= NN) return;
    unsigned short* p = c + (size_t)node * LD + fo;
    uint2 v = *(uint2*)p;
    float a0 = bfl(v.x), a1 = bfh(v.x), a2 = bfl(v.y), a3 = bfh(v.y);
    float4 sc = *(const float4*)(scale + fo);
    float4 sh = *(const float4*)(shift + fo);
    a0 = fmaf(a0, sc.x, sh.x);
    a1 = fmaf(a1, sc.y, sh.y);
    a2 = fmaf(a2, sc.z, sh.z);
    a3 = fmaf(a3, sc.w, sh.w);
    v.x = pack2(a0, a1); v.y = pack2(a2, a3);
    *(uint2*)p = v;
    *(unsigned int*)(c8 + (size_t)node * 256 + fo) = packfp8(a0, a1, a2, a3);
}

// ---------------- head GEMM via MFMA ----------------
__global__ __launch_bounds__(256) void head_mfma_kernel(const unsigned short* __restrict__ Jh,
                                                        const unsigned short* __restrict__ Wb,
                                                        const float* __restrict__ b,
                                                        float* __restrict__ out) {
    int wave = threadIdx.x >> 6;
    int lane = threadIdx.x & 63;
    int tile = blockIdx.x * 4 + wave;
    if (tile >= NT) return;
    int m = lane & 15;
    int q = lane >> 4;
    const unsigned short* arow  = Jh + (size_t)(tile * 16 + m) * LD + q * 8;
    const unsigned short* bbase = Wb + (size_t)lane * 8;
    f32x4 acc0 = {0.f, 0.f, 0.f, 0.f};
    f32x4 acc1 = {0.f, 0.f, 0.f, 0.f};
    #pragma unroll 5
    for (int kb = 0; kb < 30; kb++) {
        bf16x8 a  = *(const bf16x8*)(arow + kb * 32);
        bf16x8 b0 = *(const bf16x8*)(bbase + (size_t)kb * 512);
        bf16x8 b1 = *(const bf16x8*)(bbase + (size_t)(30 + kb) * 512);
        acc0 = __builtin_amdgcn_mfma_f32_16x16x32_bf16(a, b0, acc0, 0, 0, 0);
        acc1 = __builtin_amdgcn_mfma_f32_16x16x32_bf16(a, b1, acc1, 0, 0, 0);
    }
    int col = m;
    float b0 = b[col], b1 = b[16 + col];
    #pragma unroll
    for (int r = 0; r < 4; r++) {
        float* op = out + (size_t)(tile * 16 + q * 4 + r) * 32 + col;
        op[0]  = acc0[r] + b0;
        op[16] = acc1[r] + b1;
    }
}

// ---------------- launch ----------------

extern "C" void kernel_launch(void* const* d_in, const int* in_sizes, int n_in,
                              void* d_out, int out_size, void* d_ws, size_t ws_size,
                              hipStream_t stream) {
    const float* x      = (const float*)d_in[0];
    const int*   e1_row = (const int*)d_in[1];
    const int*   e1_col = (const int*)d_in[2];
    const float* e1_val = (const float*)d_in[3];
    const int*   e2_row = (const int*)d_in[4];
    const int*   e2_col = (const int*)d_in[5];
    const float* e2_val = (const float*)d_in[6];
    const float* W_emb  = (const float*)d_in[7];
    const float* b_emb  = (const float*)d_in[8];
    const float* bn0_g  = (const float*)d_in[9];
    const float* bn0_b  = (const float*)d_in[10];
    const float* bn1_g  = (const float*)d_in[11];
    const float* bn1_b  = (const float*)d_in[12];
    const float* W_head = (const float*)d_in[13];
    const float* b_head = (const float*)d_in[14];
    float* out = (float*)d_out;

    char* ws = (char*)d_ws;
    auto alloc = [&](size_t bytes) -> char* {
        char* p = ws;
        ws += (bytes + 255) & ~(size_t)255;
        return p;
    };
    int*   rp1   = (int*)alloc((NN + 1) * 4);
    int*   rp2   = (int*)alloc((NN + 1) * 4);
    int*   bc1   = (int*)alloc((size_t)G1B * NBKT * 4);
    int*   bc2   = (int*)alloc((size_t)G2B * NBKT * 4);
    unsigned int* Ed1 = (unsigned int*)alloc((size_t)E1N * 4);
    unsigned int* Ed2 = (unsigned int*)alloc((size_t)E2N * 4);
    float* stats = (float*)alloc(1536 * 4);
    unsigned short* Wbh  = (unsigned short*)alloc(3840 * 8 * 2);
    unsigned short* Wbe  = (unsigned short*)alloc(2048 * 8 * 2);
    unsigned char*  C1f8 = (unsigned char*)alloc((size_t)NN * 256);
    unsigned short* Jh   = (unsigned short*)alloc((size_t)NN * LD * 2);
    // temp 8B records alias Jh (dead until embed writes it)
    uint2* T1 = (uint2*)Jh;
    uint2* T2 = T1 + E1N;

    float* sum0   = stats;        float* sq0    = stats + 128;
    float* sum1   = stats + 256;  float* sq1    = stats + 512;
    float* scale0 = stats + 768;  float* shift0 = stats + 896;
    float* scale1 = stats + 1024; float* shift1 = stats + 1280;

    // CSR build (LDS counting sort) + weight packs
    zero_kernel<<<3, 256, 0, stream>>>(stats, 768);
    bucket_count_kernel<<<G1B + G2B, 256, 0, stream>>>(e1_row, e2_row, bc1, bc2);
    bucket_scan_kernel<<<1, 512, 0, stream>>>(bc1, bc2);
    bucket_place_kernel<<<G1B + G2B, 256, 0, stream>>>(e1_row, e1_col, e1_val,
                                                       e2_row, e2_col, e2_val, bc1, bc2, T1, T2);
    bucket_sort_kernel<<<2 * NBKT, 256, 0, stream>>>(bc1, T1, rp1, Ed1, bc2, T2, rp2, Ed2);
    packw_kernel<<<15, 256, 0, stream>>>(W_head, Wbh, 32, 30, 3840);
    packw_kernel<<<8, 256, 0, stream>>>(W_emb, Wbe, 64, 8, 2048);

    // embed -> Jh[:,0:64) (MFMA)  (T1/T2 dead from here on)
    embed_mfma_kernel<<<(NT + 3) / 4, 256, 0, stream>>>(x, Wbe, b_emb, Jh);

    // conv0 (bf16 h, LPR=8, 16B loads) -> Jh[:,64:192), then BN
    spmm_bf16x8_kernel<8><<<2 * ((NN + 31) / 32), 256, 0, stream>>>(rp1, Ed1, rp2, Ed2, Jh, Jh + 64);
    bn_stats_kernel<128><<<512, 256, 0, stream>>>(Jh + 64, sum0, sq0);
    bn_finalize_kernel<<<1, 128, 0, stream>>>(sum0, sq0, bn0_g, bn0_b, scale0, shift0, 128);
    bn_apply_kernel<128><<<(NN * 32 + 255) / 256, 256, 0, stream>>>(Jh + 64, scale0, shift0);

    // conv1 (bf16 c0', LPR=16, 16B loads) -> Jh[:,192:448), then BN + fp8 copy
    spmm_bf16x8_kernel<16><<<2 * (NN / 16), 256, 0, stream>>>(rp1, Ed1, rp2, Ed2, Jh + 64, Jh + 192);
    bn_stats_kernel<256><<<512, 256, 0, stream>>>(Jh + 192, sum1, sq1);
    bn_finalize_kernel<<<1, 256, 0, stream>>>(sum1, sq1, bn1_g, bn1_b, scale1, shift1, 256);
    bn_apply_fp8_kernel<<<(NN * 64 + 255) / 256, 256, 0, stream>>>(Jh + 192, C1f8, scale1, shift1);

    // conv2 (fp8 c1', LPR=16, 16 feats/lane, 16B loads) -> Jh[:,448:960)
    spmm_fp8x16_kernel<16><<<2 * (NN / 16), 256, 0, stream>>>(rp1, Ed1, rp2, Ed2, C1f8, Jh + 448);

    // head (MFMA)
    head_mfma_kernel<<<(NT + 3) / 4, 256, 0, stream>>>(Jh, Wbh, b_head, out);
}

// Round 7
// 526.601 us; speedup vs baseline: 1.2180x; 1.2013x over previous
//
#include <hip/hip_runtime.h>

// H2GCN forward, bf16 activations in fused Jh[N,960]:
//   cols [0,64)=h [64,192)=c0 [192,448)=c1 [448,960)=c2.
// CSR build = two-level LDS counting sort (r10).
// r12: v_pk_fma_f32 + 16B gathers + 8-edge batches (543.7us verified).
// r13/r14 (XCD-pinned CONCURRENT slices): FAILED (FETCH 230->417MB).
// r15: column-grouped edges (sort key = localrow*7 + col>>13): 533.9us,
//   FETCH 230->212MB. KEPT. Verdict after r13/r15/r16: ~3.5TB/s miss-path
//   rate for the random gather is structural; stop chasing it.
// r16 (SERIALIZED per-slice launches): REGRESSED 534->641. REVERTED.
// r17: CHUNK 8192->2048 fixed bucket_place grid-starvation (56.5->~20us,
//   294->1173 blocks) BUT single-block bucket_scan went 8->128us (1173
//   serial strided iters x2). Net REGRESSED 534->633.
// r18: keep CHUNK=2048; replace the scan with 3 parallel kernels:
//   scan_tot (782 blks: per-bucket column reduce), scan_base (1 blk:
//   391-elem Hillis-Steele per graph), scan_apply (782 blks: per-bucket
//   parallel exclusive scan over G values + base). Byte-identical bc
//   output; ~128us -> ~13us.
// fp8 ONLY at the leaf conv (r11: fp8 earlier cascades, absmax FAIL).
// Embed + Head: MFMA 16x16x32 bf16, weights pre-packed to B-fragment layout.

#define NN  50000
#define E1N 800000
#define E2N 1600000
#define LD  960
#define NT  3125         // 16-node tiles
#define NBKT 391         // 128-row buckets
#define CHUNK 2048
#define G1B 391          // ceil(E1N/CHUNK)
#define G2B 782          // ceil(E2N/CHUNK)
#define NCG 7            // column groups of 8192 nodes

typedef short bf16x8 __attribute__((ext_vector_type(8)));
typedef float f32x4  __attribute__((ext_vector_type(4)));
typedef float f32x2  __attribute__((ext_vector_type(2)));

__device__ __forceinline__ float bfl(unsigned int w) { return __uint_as_float(w << 16); }
__device__ __forceinline__ float bfh(unsigned int w) { return __uint_as_float(w & 0xFFFF0000u); }
__device__ __forceinline__ float bf2f(unsigned short u) { return __uint_as_float(((unsigned int)u) << 16); }
__device__ __forceinline__ unsigned short f2bf(float f) {         // RNE
    unsigned int u = __float_as_uint(f);
    u += 0x7FFFu + ((u >> 16) & 1u);
    return (unsigned short)(u >> 16);
}
__device__ __forceinline__ unsigned int pack2(float a, float b) {
    return (unsigned int)f2bf(a) | ((unsigned int)f2bf(b) << 16);
}
__device__ __forceinline__ unsigned int packfp8(float a, float b, float c, float d) {
    int w = __builtin_amdgcn_cvt_pk_fp8_f32(a, b, 0, false);
    w     = __builtin_amdgcn_cvt_pk_fp8_f32(c, d, w, true);
    return (unsigned int)w;
}
// packed f32 fma (v_pk_fma_f32 on gfx950); identical per-lane rounding to fmaf
__device__ __forceinline__ f32x2 pkfma(f32x2 a, f32x2 b, f32x2 c) {
#if __has_builtin(__builtin_elementwise_fma)
    return __builtin_elementwise_fma(a, b, c);
#else
    return (f32x2){fmaf(a[0], b[0], c[0]), fmaf(a[1], b[1], c[1])};
#endif
}
// bf16 pair (packed in a u32) -> f32x2 {lo, hi}
__device__ __forceinline__ f32x2 bf2(unsigned int w) {
    return (f32x2){bfl(w), bfh(w)};
}

// ---------------- CSR build ----------------

__global__ __launch_bounds__(256) void zero_kernel(float* c, int nc) {
    int i = blockIdx.x * 256 + threadIdx.x;
    if (i < nc) c[i] = 0.f;
}

__global__ __launch_bounds__(256) void bucket_count_kernel(const int* __restrict__ r1,
                                                           const int* __restrict__ r2,
                                                           int* __restrict__ bc1, int* __restrict__ bc2) {
    __shared__ int cnt[NBKT];
    for (int t = threadIdx.x; t < NBKT; t += 256) cnt[t] = 0;
    __syncthreads();
    int blk = blockIdx.x;
    const int* r; int base, lim; int* bc;
    if (blk < G1B) { r = r1; base = blk * CHUNK; lim = min(base + CHUNK, E1N); bc = bc1 + blk * NBKT; }
    else { int b2 = blk - G1B; r = r2; base = b2 * CHUNK; lim = min(base + CHUNK, E2N); bc = bc2 + b2 * NBKT; }
    for (int i = base + threadIdx.x; i < lim; i += 256)
        atomicAdd(&cnt[r[i] >> 7], 1);
    __syncthreads();
    for (int t = threadIdx.x; t < NBKT; t += 256) bc[t] = cnt[t];
}

// scan phase 1: per-bucket totals across chunk-blocks (parallel reduce)
__global__ __launch_bounds__(256) void scan_tot_kernel(const int* __restrict__ bc1,
                                                       const int* __restrict__ bc2,
                                                       int* __restrict__ tot) {
    int b = blockIdx.x % NBKT;
    int g = blockIdx.x / NBKT;
    const int* bc = g ? bc2 : bc1;
    int G = g ? G2B : G1B;
    int s = 0;
    for (int i = threadIdx.x; i < G; i += 256) s += bc[(size_t)i * NBKT + b];
    __shared__ int red[256];
    red[threadIdx.x] = s;
    __syncthreads();
    for (int off = 128; off; off >>= 1) {
        if ((int)threadIdx.x < off) red[threadIdx.x] += red[threadIdx.x + off];
        __syncthreads();
    }
    if (threadIdx.x == 0) tot[g * NBKT + b] = red[0];
}

// scan phase 2: exclusive bases over buckets (per graph), single block
__global__ __launch_bounds__(512) void scan_base_kernel(const int* __restrict__ tot,
                                                        int* __restrict__ base) {
    __shared__ int s[512];
    int t = threadIdx.x;
    int v1 = (t < NBKT) ? tot[t] : 0;
    s[t] = v1;
    __syncthreads();
    for (int off = 1; off < 512; off <<= 1) {
        int v = (t >= off) ? s[t - off] : 0;
        __syncthreads(); s[t] += v; __syncthreads();
    }
    if (t < NBKT) base[t] = s[t] - v1;
    __syncthreads();
    int v2 = (t < NBKT) ? tot[NBKT + t] : 0;
    s[t] = v2;
    __syncthreads();
    for (int off = 1; off < 512; off <<= 1) {
        int v = (t >= off) ? s[t - off] : 0;
        __syncthreads(); s[t] += v; __syncthreads();
    }
    if (t < NBKT) base[NBKT + t] = s[t] - v2;
}

// scan phase 3: per-bucket exclusive running prefix over chunk-blocks + base
__global__ __launch_bounds__(256) void scan_apply_kernel(int* __restrict__ bc1, int* __restrict__ bc2,
                                                         const int* __restrict__ base) {
    int b = blockIdx.x % NBKT;
    int g = blockIdx.x / NBKT;
    int* bc = g ? bc2 : bc1;
    int G = g ? G2B : G1B;
    int t = threadIdx.x;
    int vals[4];
    int loc = 0;
    #pragma unroll
    for (int k = 0; k < 4; k++) {
        int idx = t * 4 + k;
        int v = (idx < G) ? bc[(size_t)idx * NBKT + b] : 0;
        vals[k] = v; loc += v;
    }
    __shared__ int s[256];
    s[t] = loc;
    __syncthreads();
    for (int off = 1; off < 256; off <<= 1) {
        int v = (t >= off) ? s[t - off] : 0;
        __syncthreads(); s[t] += v; __syncthreads();
    }
    int run = base[g * NBKT + b] + ((t > 0) ? s[t - 1] : 0);
    #pragma unroll
    for (int k = 0; k < 4; k++) {
        int idx = t * 4 + k;
        if (idx < G) { int old = vals[k]; bc[(size_t)idx * NBKT + b] = run; run += old; }
    }
}

__global__ __launch_bounds__(256) void bucket_place_kernel(
        const int* __restrict__ r1, const int* __restrict__ c1, const float* __restrict__ v1,
        const int* __restrict__ r2, const int* __restrict__ c2, const float* __restrict__ v2,
        const int* __restrict__ bc1, const int* __restrict__ bc2,
        uint2* __restrict__ T1, uint2* __restrict__ T2) {
    __shared__ int pos[NBKT];
    int blk = blockIdx.x;
    const int *r, *c; const float* v; int base, lim; const int* bc; uint2* T;
    if (blk < G1B) { r = r1; c = c1; v = v1; base = blk * CHUNK; lim = min(base + CHUNK, E1N);
                     bc = bc1 + blk * NBKT; T = T1; }
    else { int b2 = blk - G1B; r = r2; c = c2; v = v2; base = b2 * CHUNK; lim = min(base + CHUNK, E2N);
           bc = bc2 + b2 * NBKT; T = T2; }
    for (int t = threadIdx.x; t < NBKT; t += 256) pos[t] = bc[t];
    __syncthreads();
    for (int i = base + threadIdx.x; i < lim; i += 256) {
        int row = r[i];
        int p = atomicAdd(&pos[row >> 7], 1);
        T[p] = make_uint2(((unsigned)c[i] << 16) | (unsigned)row, __float_as_uint(v[i]));
    }
}

// Second-level sort: key = localrow*NCG + colgroup (col>>13). Produces CSR
// where each row's edges are grouped by ascending 8192-node column group.
__global__ __launch_bounds__(256) void bucket_sort_kernel(
        const int* __restrict__ bb1, const uint2* __restrict__ T1, int* __restrict__ rp1, unsigned int* __restrict__ Ed1,
        const int* __restrict__ bb2, const uint2* __restrict__ T2, int* __restrict__ rp2, unsigned int* __restrict__ Ed2) {
    int b = blockIdx.x % NBKT;
    int g = blockIdx.x / NBKT;
    const int* bb = g ? bb2 : bb1;
    const uint2* T = g ? T2 : T1;
    int* rp = g ? rp2 : rp1;
    unsigned int* Ed = g ? Ed2 : Ed1;
    int EN = g ? E2N : E1N;
    int beg = bb[b];
    int end = (b == NBKT - 1) ? EN : bb[b + 1];
    int R0 = b * 128;
    int nrows = min(128, NN - R0);
    // keys: 0 .. 128*NCG-1 = 895. counts stored at cnt[key+1]; cnt[0]=0.
    __shared__ int cnt[1024];
    __shared__ int cur[896];
    __shared__ int ps[256];
    int t = threadIdx.x;
    for (int i = t; i < 1024; i += 256) cnt[i] = 0;
    __syncthreads();
    for (int i = beg + t; i < end; i += 256) {
        unsigned int x = T[i].x;
        int lr = (x & 0xFFFFu) & 127;
        int cg = (int)(x >> 29);            // (col>>13): col in bits [16,32) -> >>29
        atomicAdd(&cnt[lr * NCG + cg + 1], 1);
    }
    __syncthreads();
    // inclusive scan of cnt[0..1023], 4 elems/thread
    int b0 = t * 4;
    int c0 = cnt[b0], c1 = cnt[b0 + 1], c2 = cnt[b0 + 2], c3 = cnt[b0 + 3];
    int s1 = c0 + c1, s2 = s1 + c2, s3 = s2 + c3;
    ps[t] = s3;
    __syncthreads();
    for (int off = 1; off < 256; off <<= 1) {
        int v = (t >= off) ? ps[t - off] : 0;
        __syncthreads(); ps[t] += v; __syncthreads();
    }
    int base = (t > 0) ? ps[t - 1] : 0;
    cnt[b0] = base + c0; cnt[b0 + 1] = base + s1;
    cnt[b0 + 2] = base + s2; cnt[b0 + 3] = base + s3;
    __syncthreads();
    // cnt[k] (inclusive scan at index k) == exclusive prefix for key k
    for (int k = t; k < 896; k += 256) cur[k] = beg + cnt[k];
    if (t < nrows) rp[R0 + t] = beg + cnt[t * NCG];
    if (b == NBKT - 1 && t == 0) rp[NN] = end;
    __syncthreads();
    for (int i = beg + t; i < end; i += 256) {
        uint2 rec = T[i];
        int lr = (rec.x & 0xFFFFu) & 127;
        int cg = (int)(rec.x >> 29);
        int p = atomicAdd(&cur[lr * NCG + cg], 1);
        Ed[p] = (rec.x & 0xFFFF0000u) | (unsigned)f2bf(__uint_as_float(rec.y));
    }
}

// ---------------- weight -> bf16 B-fragment pack ----------------
__global__ __launch_bounds__(256) void packw_kernel(const float* __restrict__ W, unsigned short* __restrict__ Wb,
                                                    int NC, int kbs, int total) {
    int i = blockIdx.x * 256 + threadIdx.x;
    if (i >= total) return;
    int lane  = i & 63;
    int kb    = (i >> 6) % kbs;
    int ctile = i / (kbs * 64);
    int n  = ctile * 16 + (lane & 15);
    int k0 = kb * 32 + (lane >> 4) * 8;
    unsigned short v[8];
    #pragma unroll
    for (int j = 0; j < 8; j++) v[j] = f2bf(W[(k0 + j) * NC + n]);
    *(uint4*)(Wb + (size_t)i * 8) = *(uint4*)v;
}

// ---------------- embed via MFMA ----------------
__global__ __launch_bounds__(256) void embed_mfma_kernel(const float* __restrict__ x,
                                                         const unsigned short* __restrict__ Wb,
                                                         const float* __restrict__ bias,
                                                         unsigned short* __restrict__ Jh) {
    int wave = threadIdx.x >> 6;
    int lane = threadIdx.x & 63;
    int tile = blockIdx.x * 4 + wave;
    if (tile >= NT) return;
    int m = lane & 15;
    int q = lane >> 4;
    const float* xr = x + (size_t)(tile * 16 + m) * 256 + q * 8;
    const unsigned short* bbase = Wb + (size_t)lane * 8;
    f32x4 acc[4];
    #pragma unroll
    for (int ct = 0; ct < 4; ct++) acc[ct] = (f32x4){0.f, 0.f, 0.f, 0.f};
    #pragma unroll
    for (int kb = 0; kb < 8; kb++) {
        float4 xa = *(const float4*)(xr + kb * 32);
        float4 xb = *(const float4*)(xr + kb * 32 + 4);
        unsigned short av[8];
        av[0] = f2bf(xa.x); av[1] = f2bf(xa.y); av[2] = f2bf(xa.z); av[3] = f2bf(xa.w);
        av[4] = f2bf(xb.x); av[5] = f2bf(xb.y); av[6] = f2bf(xb.z); av[7] = f2bf(xb.w);
        bf16x8 a = *(bf16x8*)av;
        #pragma unroll
        for (int ct = 0; ct < 4; ct++) {
            bf16x8 bfr = *(const bf16x8*)(bbase + (size_t)(ct * 8 + kb) * 512);
            acc[ct] = __builtin_amdgcn_mfma_f32_16x16x32_bf16(a, bfr, acc[ct], 0, 0, 0);
        }
    }
    #pragma unroll
    for (int ct = 0; ct < 4; ct++) {
        int col = ct * 16 + m;
        float bb = bias[col];
        #pragma unroll
        for (int r = 0; r < 4; r++) {
            float v = fmaxf(acc[ct][r] + bb, 0.f);
            Jh[(size_t)(tile * 16 + q * 4 + r) * LD + col] = f2bf(v);
        }
    }
}

// ---------------- pull SPMM, bf16 source, 8 feats/lane, 16B loads ----------------
// LPR=8  -> conv0 (64-feat source), LPR=16 -> conv1 (128-feat source)
template <int LPR>
__global__ __launch_bounds__(256) void spmm_bf16x8_kernel(
        const int* __restrict__ rp1, const unsigned int* __restrict__ ed1,
        const int* __restrict__ rp2, const unsigned int* __restrict__ ed2,
        const unsigned short* __restrict__ src, unsigned short* __restrict__ dst) {
    constexpr int ROWS = 64 / LPR;
    constexpr int SRCF = LPR * 8;
    constexpr int RPB  = ROWS * 4;
    constexpr int GB   = (NN + RPB - 1) / RPB;
    int g    = (blockIdx.x >= GB) ? 1 : 0;
    int bx   = blockIdx.x - g * GB;
    int wave = threadIdx.x >> 6;
    int lane = threadIdx.x & 63;
    int grp  = lane / LPR;
    int sub  = lane % LPR;
    int row  = (bx * 4 + wave) * ROWS + grp;
    const int*          rp = g ? rp2 : rp1;
    const unsigned int* ed = g ? ed2 : ed1;
    bool ok = row < NN;
    int beg = 0, end = 0;
    if (ok) { beg = rp[row]; end = rp[row + 1]; }

    f32x2 acc[4];
    #pragma unroll
    for (int u = 0; u < 4; u++) acc[u] = (f32x2){0.f, 0.f};
    const unsigned short* sbase = src + sub * 8;

    int j = beg;
    for (; j + 8 <= end; j += 8) {
        unsigned int e[8];
        #pragma unroll
        for (int u = 0; u < 8; u++) e[u] = ed[j + u];
        uint4 s[8];
        #pragma unroll
        for (int u = 0; u < 8; u++) s[u] = *(const uint4*)(sbase + (size_t)(e[u] >> 16) * LD);
        #pragma unroll
        for (int u = 0; u < 8; u++) {
            float v = bfl(e[u]);
            f32x2 vv = (f32x2){v, v};
            acc[0] = pkfma(vv, bf2(s[u].x), acc[0]);
            acc[1] = pkfma(vv, bf2(s[u].y), acc[1]);
            acc[2] = pkfma(vv, bf2(s[u].z), acc[2]);
            acc[3] = pkfma(vv, bf2(s[u].w), acc[3]);
        }
    }
    for (; j < end; j++) {
        unsigned int e = ed[j];
        float v = bfl(e);
        f32x2 vv = (f32x2){v, v};
        uint4 s = *(const uint4*)(sbase + (size_t)(e >> 16) * LD);
        acc[0] = pkfma(vv, bf2(s.x), acc[0]);
        acc[1] = pkfma(vv, bf2(s.y), acc[1]);
        acc[2] = pkfma(vv, bf2(s.z), acc[2]);
        acc[3] = pkfma(vv, bf2(s.w), acc[3]);
    }

    if (ok) {
        unsigned short* dp = dst + (size_t)row * LD + g * SRCF + sub * 8;
        uint4 o;
        o.x = pack2(acc[0][0], acc[0][1]); o.y = pack2(acc[1][0], acc[1][1]);
        o.z = pack2(acc[2][0], acc[2][1]); o.w = pack2(acc[3][0], acc[3][1]);
        *(uint4*)dp = o;
    }
}

// ---------------- pull SPMM, fp8 source, 16 feats/lane, 16B loads (conv2) ----------------
template <int LPR>
__global__ __launch_bounds__(256) void spmm_fp8x16_kernel(
        const int* __restrict__ rp1, const unsigned int* __restrict__ ed1,
        const int* __restrict__ rp2, const unsigned int* __restrict__ ed2,
        const unsigned char* __restrict__ src8,   // [N, LPR*16] fp8
        unsigned short* __restrict__ dst) {
    constexpr int ROWS = 64 / LPR;     // 4
    constexpr int SRCF = LPR * 16;     // 256
    constexpr int RPB  = ROWS * 4;
    constexpr int GB   = (NN + RPB - 1) / RPB;
    int g    = (blockIdx.x >= GB) ? 1 : 0;
    int bx   = blockIdx.x - g * GB;
    int wave = threadIdx.x >> 6;
    int lane = threadIdx.x & 63;
    int grp  = lane / LPR;
    int sub  = lane % LPR;
    int row  = (bx * 4 + wave) * ROWS + grp;
    const int*          rp = g ? rp2 : rp1;
    const unsigned int* ed = g ? ed2 : ed1;
    bool ok = row < NN;
    int beg = 0, end = 0;
    if (ok) { beg = rp[row]; end = rp[row + 1]; }

    f32x2 acc[8];
    #pragma unroll
    for (int u = 0; u < 8; u++) acc[u] = (f32x2){0.f, 0.f};
    const unsigned char* sbase = src8 + sub * 16;

    int j = beg;
    for (; j + 8 <= end; j += 8) {
        unsigned int e[8];
        #pragma unroll
        for (int u = 0; u < 8; u++) e[u] = ed[j + u];
        uint4 s[8];
        #pragma unroll
        for (int u = 0; u < 8; u++) s[u] = *(const uint4*)(sbase + (size_t)(e[u] >> 16) * SRCF);
        #pragma unroll
        for (int u = 0; u < 8; u++) {
            float v = bfl(e[u]);
            f32x2 vv = (f32x2){v, v};
            acc[0] = pkfma(vv, __builtin_amdgcn_cvt_pk_f32_fp8(s[u].x, false), acc[0]);
            acc[1] = pkfma(vv, __builtin_amdgcn_cvt_pk_f32_fp8(s[u].x, true),  acc[1]);
            acc[2] = pkfma(vv, __builtin_amdgcn_cvt_pk_f32_fp8(s[u].y, false), acc[2]);
            acc[3] = pkfma(vv, __builtin_amdgcn_cvt_pk_f32_fp8(s[u].y, true),  acc[3]);
            acc[4] = pkfma(vv, __builtin_amdgcn_cvt_pk_f32_fp8(s[u].z, false), acc[4]);
            acc[5] = pkfma(vv, __builtin_amdgcn_cvt_pk_f32_fp8(s[u].z, true),  acc[5]);
            acc[6] = pkfma(vv, __builtin_amdgcn_cvt_pk_f32_fp8(s[u].w, false), acc[6]);
            acc[7] = pkfma(vv, __builtin_amdgcn_cvt_pk_f32_fp8(s[u].w, true),  acc[7]);
        }
    }
    for (; j < end; j++) {
        unsigned int e = ed[j];
        float v = bfl(e);
        f32x2 vv = (f32x2){v, v};
        uint4 s = *(const uint4*)(sbase + (size_t)(e >> 16) * SRCF);
        acc[0] = pkfma(vv, __builtin_amdgcn_cvt_pk_f32_fp8(s.x, false), acc[0]);
        acc[1] = pkfma(vv, __builtin_amdgcn_cvt_pk_f32_fp8(s.x, true),  acc[1]);
        acc[2] = pkfma(vv, __builtin_amdgcn_cvt_pk_f32_fp8(s.y, false), acc[2]);
        acc[3] = pkfma(vv, __builtin_amdgcn_cvt_pk_f32_fp8(s.y, true),  acc[3]);
        acc[4] = pkfma(vv, __builtin_amdgcn_cvt_pk_f32_fp8(s.z, false), acc[4]);
        acc[5] = pkfma(vv, __builtin_amdgcn_cvt_pk_f32_fp8(s.z, true),  acc[5]);
        acc[6] = pkfma(vv, __builtin_amdgcn_cvt_pk_f32_fp8(s.w, false), acc[6]);
        acc[7] = pkfma(vv, __builtin_amdgcn_cvt_pk_f32_fp8(s.w, true),  acc[7]);
    }

    if (ok) {
        unsigned short* dp = dst + (size_t)row * LD + g * SRCF + sub * 16;
        uint4 o1, o2;
        o1.x = pack2(acc[0][0], acc[0][1]); o1.y = pack2(acc[1][0], acc[1][1]);
        o1.z = pack2(acc[2][0], acc[2][1]); o1.w = pack2(acc[3][0], acc[3][1]);
        o2.x = pack2(acc[4][0], acc[4][1]); o2.y = pack2(acc[5][0], acc[5][1]);
        o2.z = pack2(acc[6][0], acc[6][1]); o2.w = pack2(acc[7][0], acc[7][1]);
        *(uint4*)dp = o1;
        *(uint4*)(dp + 8) = o2;
    }
}

// ---------------- BN stats / finalize / apply ----------------
template <int F>
__global__ __launch_bounds__(256) void bn_stats_kernel(const unsigned short* __restrict__ c,
                                                       float* sum, float* sumsq) {
    constexpr int SL = 256 / F;
    int f  = threadIdx.x % F;
    int sl = threadIdx.x / F;
    float s = 0.f, ss = 0.f;
    for (int r = blockIdx.x * SL + sl; r < NN; r += gridDim.x * SL) {
        float v = bf2f(c[(size_t)r * LD + f]);
        s += v; ss += v * v;
    }
    __shared__ float ls[256], lss[256];
    ls[threadIdx.x] = s; lss[threadIdx.x] = ss;
    __syncthreads();
    if (sl == 0) {
        #pragma unroll
        for (int u = 1; u < SL; u++) { s += ls[f + u * F]; ss += lss[f + u * F]; }
        atomicAdd(&sum[f], s);
        atomicAdd(&sumsq[f], ss);
    }
}

__global__ void bn_finalize_kernel(const float* sum, const float* sumsq, const float* __restrict__ gamma,
                                   const float* __restrict__ beta, float* scale, float* shift, int F) {
    int f = blockIdx.x * blockDim.x + threadIdx.x;
    if (f >= F) return;
    float m   = sum[f] * (1.0f / NN);
    float var = sumsq[f] * (1.0f / NN) - m * m;
    float sc  = gamma[f] * rsqrtf(var + 1e-5f);
    scale[f] = sc;
    shift[f] = beta[f] - m * sc;
}

template <int F>
__global__ __launch_bounds__(256) void bn_apply_kernel(unsigned short* __restrict__ c,
                                                       const float* __restrict__ scale,
                                                       const float* __restrict__ shift) {
    constexpr int FV = F / 4;
    int idx  = blockIdx.x * 256 + threadIdx.x;
    int node = idx / FV;
    int fo   = (idx % FV) * 4;
    if (node >= NN) return;
    unsigned short* p = c + (size_t)node * LD + fo;
    uint2 v = *(uint2*)p;
    float a0 = bfl(v.x), a1 = bfh(v.x), a2 = bfl(v.y), a3 = bfh(v.y);
    float4 sc = *(const float4*)(scale + fo);
    float4 sh = *(const float4*)(shift + fo);
    a0 = fmaf(a0, sc.x, sh.x);
    a1 = fmaf(a1, sc.y, sh.y);
    a2 = fmaf(a2, sc.z, sh.z);
    a3 = fmaf(a3, sc.w, sh.w);
    v.x = pack2(a0, a1); v.y = pack2(a2, a3);
    *(uint2*)p = v;
}

// BN apply on c1 (F=256): bf16 in-place AND fp8 copy for conv2's gather
__global__ __launch_bounds__(256) void bn_apply_fp8_kernel(unsigned short* __restrict__ c,
                                                           unsigned char* __restrict__ c8,
                                                           const float* __restrict__ scale,
                                                           const float* __restrict__ shift) {
    int idx  = blockIdx.x * 256 + threadIdx.x;
    int node = idx >> 6;
    int fo   = (idx & 63) * 4;
    if (node >= NN) return;
    unsigned short* p = c + (size_t)node * LD + fo;
    uint2 v = *(uint2*)p;
    float a0 = bfl(v.x), a1 = bfh(v.x), a2 = bfl(v.y), a3 = bfh(v.y);
    float4 sc = *(const float4*)(scale + fo);
    float4 sh = *(const float4*)(shift + fo);
    a0 = fmaf(a0, sc.x, sh.x);
    a1 = fmaf(a1, sc.y, sh.y);
    a2 = fmaf(a2, sc.z, sh.z);
    a3 = fmaf(a3, sc.w, sh.w);
    v.x = pack2(a0, a1); v.y = pack2(a2, a3);
    *(uint2*)p = v;
    *(unsigned int*)(c8 + (size_t)node * 256 + fo) = packfp8(a0, a1, a2, a3);
}

// ---------------- head GEMM via MFMA ----------------
__global__ __launch_bounds__(256) void head_mfma_kernel(const unsigned short* __restrict__ Jh,
                                                        const unsigned short* __restrict__ Wb,
                                                        const float* __restrict__ b,
                                                        float* __restrict__ out) {
    int wave = threadIdx.x >> 6;
    int lane = threadIdx.x & 63;
    int tile = blockIdx.x * 4 + wave;
    if (tile >= NT) return;
    int m = lane & 15;
    int q = lane >> 4;
    const unsigned short* arow  = Jh + (size_t)(tile * 16 + m) * LD + q * 8;
    const unsigned short* bbase = Wb + (size_t)lane * 8;
    f32x4 acc0 = {0.f, 0.f, 0.f, 0.f};
    f32x4 acc1 = {0.f, 0.f, 0.f, 0.f};
    #pragma unroll 5
    for (int kb = 0; kb < 30; kb++) {
        bf16x8 a  = *(const bf16x8*)(arow + kb * 32);
        bf16x8 b0 = *(const bf16x8*)(bbase + (size_t)kb * 512);
        bf16x8 b1 = *(const bf16x8*)(bbase + (size_t)(30 + kb) * 512);
        acc0 = __builtin_amdgcn_mfma_f32_16x16x32_bf16(a, b0, acc0, 0, 0, 0);
        acc1 = __builtin_amdgcn_mfma_f32_16x16x32_bf16(a, b1, acc1, 0, 0, 0);
    }
    int col = m;
    float b0 = b[col], b1 = b[16 + col];
    #pragma unroll
    for (int r = 0; r < 4; r++) {
        float* op = out + (size_t)(tile * 16 + q * 4 + r) * 32 + col;
        op[0]  = acc0[r] + b0;
        op[16] = acc1[r] + b1;
    }
}

// ---------------- launch ----------------

extern "C" void kernel_launch(void* const* d_in, const int* in_sizes, int n_in,
                              void* d_out, int out_size, void* d_ws, size_t ws_size,
                              hipStream_t stream) {
    const float* x      = (const float*)d_in[0];
    const int*   e1_row = (const int*)d_in[1];
    const int*   e1_col = (const int*)d_in[2];
    const float* e1_val = (const float*)d_in[3];
    const int*   e2_row = (const int*)d_in[4];
    const int*   e2_col = (const int*)d_in[5];
    const float* e2_val = (const float*)d_in[6];
    const float* W_emb  = (const float*)d_in[7];
    const float* b_emb  = (const float*)d_in[8];
    const float* bn0_g  = (const float*)d_in[9];
    const float* bn0_b  = (const float*)d_in[10];
    const float* bn1_g  = (const float*)d_in[11];
    const float* bn1_b  = (const float*)d_in[12];
    const float* W_head = (const float*)d_in[13];
    const float* b_head = (const float*)d_in[14];
    float* out = (float*)d_out;

    char* ws = (char*)d_ws;
    auto alloc = [&](size_t bytes) -> char* {
        char* p = ws;
        ws += (bytes + 255) & ~(size_t)255;
        return p;
    };
    int*   rp1   = (int*)alloc((NN + 1) * 4);
    int*   rp2   = (int*)alloc((NN + 1) * 4);
    int*   bc1   = (int*)alloc((size_t)G1B * NBKT * 4);
    int*   bc2   = (int*)alloc((size_t)G2B * NBKT * 4);
    int*   tot   = (int*)alloc(2 * NBKT * 4);
    int*   basep = (int*)alloc(2 * NBKT * 4);
    unsigned int* Ed1 = (unsigned int*)alloc((size_t)E1N * 4);
    unsigned int* Ed2 = (unsigned int*)alloc((size_t)E2N * 4);
    float* stats = (float*)alloc(1536 * 4);
    unsigned short* Wbh  = (unsigned short*)alloc(3840 * 8 * 2);
    unsigned short* Wbe  = (unsigned short*)alloc(2048 * 8 * 2);
    unsigned char*  C1f8 = (unsigned char*)alloc((size_t)NN * 256);
    unsigned short* Jh   = (unsigned short*)alloc((size_t)NN * LD * 2);
    // temp 8B records alias Jh (dead until embed writes it)
    uint2* T1 = (uint2*)Jh;
    uint2* T2 = T1 + E1N;

    float* sum0   = stats;        float* sq0    = stats + 128;
    float* sum1   = stats + 256;  float* sq1    = stats + 512;
    float* scale0 = stats + 768;  float* shift0 = stats + 896;
    float* scale1 = stats + 1024; float* shift1 = stats + 1280;

    // CSR build (LDS counting sort) + weight packs
    zero_kernel<<<3, 256, 0, stream>>>(stats, 768);
    bucket_count_kernel<<<G1B + G2B, 256, 0, stream>>>(e1_row, e2_row, bc1, bc2);
    scan_tot_kernel<<<2 * NBKT, 256, 0, stream>>>(bc1, bc2, tot);
    scan_base_kernel<<<1, 512, 0, stream>>>(tot, basep);
    scan_apply_kernel<<<2 * NBKT, 256, 0, stream>>>(bc1, bc2, basep);
    bucket_place_kernel<<<G1B + G2B, 256, 0, stream>>>(e1_row, e1_col, e1_val,
                                                       e2_row, e2_col, e2_val, bc1, bc2, T1, T2);
    bucket_sort_kernel<<<2 * NBKT, 256, 0, stream>>>(bc1, T1, rp1, Ed1, bc2, T2, rp2, Ed2);
    packw_kernel<<<15, 256, 0, stream>>>(W_head, Wbh, 32, 30, 3840);
    packw_kernel<<<8, 256, 0, stream>>>(W_emb, Wbe, 64, 8, 2048);

    // embed -> Jh[:,0:64) (MFMA)  (T1/T2 dead from here on)
    embed_mfma_kernel<<<(NT + 3) / 4, 256, 0, stream>>>(x, Wbe, b_emb, Jh);

    // conv0 (bf16 h, LPR=8, 16B loads) -> Jh[:,64:192), then BN
    spmm_bf16x8_kernel<8><<<2 * ((NN + 31) / 32), 256, 0, stream>>>(rp1, Ed1, rp2, Ed2, Jh, Jh + 64);
    bn_stats_kernel<128><<<512, 256, 0, stream>>>(Jh + 64, sum0, sq0);
    bn_finalize_kernel<<<1, 128, 0, stream>>>(sum0, sq0, bn0_g, bn0_b, scale0, shift0, 128);
    bn_apply_kernel<128><<<(NN * 32 + 255) / 256, 256, 0, stream>>>(Jh + 64, scale0, shift0);

    // conv1 (bf16 c0', LPR=16, 16B loads) -> Jh[:,192:448), then BN + fp8 copy
    spmm_bf16x8_kernel<16><<<2 * (NN / 16), 256, 0, stream>>>(rp1, Ed1, rp2, Ed2, Jh + 64, Jh + 192);
    bn_stats_kernel<256><<<512, 256, 0, stream>>>(Jh + 192, sum1, sq1);
    bn_finalize_kernel<<<1, 256, 0, stream>>>(sum1, sq1, bn1_g, bn1_b, scale1, shift1, 256);
    bn_apply_fp8_kernel<<<(NN * 64 + 255) / 256, 256, 0, stream>>>(Jh + 192, C1f8, scale1, shift1);

    // conv2 (fp8 c1', LPR=16, 16 feats/lane, 16B loads) -> Jh[:,448:960)
    spmm_fp8x16_kernel<16><<<2 * (NN / 16), 256, 0, stream>>>(rp1, Ed1, rp2, Ed2, C1f8, Jh + 448);

    // head (MFMA)
    head_mfma_kernel<<<(NT + 3) / 4, 256, 0, stream>>>(Jh, Wbh, b_head, out);
}